// Round 5
// baseline (1635.217 us; speedup 1.0000x reference)
//
#include <hip/hip_runtime.h>
#include <hip/hip_bf16.h>
#include <stdint.h>

#define HD   512   // hidden dim H
#define ID   128   // input dim I
#define NCLS 100   // num classes
#define TT   512   // sequence length T
#define BB   128   // batch B
#define NEMB 101   // NC + 1 embedding rows
#define NGRP 32    // independent batch groups
#define GWG  8     // workgroups per group (sync clique)
#define RPG  4     // batch rows per group
#define COLS 64    // hidden cols per WG (GWG*COLS == HD)
#define THR  512   // threads per recurrence WG (8 waves, 2 waves/SIMD)
#define CPAD 640   // LDS C row stride in floats: 32 chunks x (16 data + 4 pad)
#define PST  5     // partials slot stride in float2 (4 rows + 1 pad)

// workspace layout (bytes)
#define WS_FLAG 0
#define WS_BAR  4096                   // u32 bars[NGRP*32] (128 B apart)
#define WS_G    65536                  // float G[101][2048]  (808 KB)
#define WS_C0   (1u * 1024 * 1024)     // float C0[128][512]  (256 KB)
#define WS_C1   (WS_C0 + 262144)       // float C1[128][512]  (256 KB)
#define WS_HFB  (WS_C1 + 262144)       // float Hfb[128][512] (256 KB)
#define NBARU   4096                   // u32s to zero

using bf16 = __hip_bfloat16;
typedef float v2f __attribute__((ext_vector_type(2)));

__device__ __forceinline__ float b2f(bf16 v) { return __bfloat162float(v); }
__device__ __forceinline__ float sigf(float x) { return 1.0f / (1.0f + expf(-x)); }

// Agent-scope accessors — proven r6-r17. Serviced at the die-level coherence
// point: always correct, ~600-900 cy.
// NOTE (r3/r4 post-mortem): the sc0 "same-XCD L2" transport is REFUTED on
// gfx950 — identical deterministic corruption across two guard designs;
// sc0 loads allocate/hit L1 (CU-scope hint, not an L1 bypass), so staged
// reads served stale L1 lines from 2 steps prior. The r4 probe passed
// spuriously because the rank's own sc0 store invalidated the polluted L1
// line before the check. No gfx950 flag forces L1-miss-but-L2-hit. Agent
// scope is the only correct cross-WG transport; do not retry sc0.
__device__ __forceinline__ float cld(const float* p) {
    return __hip_atomic_load(p, __ATOMIC_RELAXED, __HIP_MEMORY_SCOPE_AGENT);
}
__device__ __forceinline__ void cst(float* p, float v) {
    __hip_atomic_store(p, v, __ATOMIC_RELAXED, __HIP_MEMORY_SCOPE_AGENT);
}

template <bool BF>
__device__ __forceinline__ float ldv(const void* p, int i) {
    if constexpr (BF) return b2f(((const bf16*)p)[i]);
    else              return ((const float*)p)[i];
}

// padded Cs index for h' (16 data floats + 4 pad per chunk)
__device__ __forceinline__ int cpi(int h) { return (h >> 4) * 20 + (h & 15); }

// ---------------------------------------------------------------------------
// Group barrier — r13's best-measured flavor (RMW-IF + tight poll). Leading
// __syncthreads drains all waves' sc1 C stores before the arrive.
// ---------------------------------------------------------------------------
__device__ __forceinline__ void gbarrier(unsigned* cnt, unsigned* iter) {
    __syncthreads();
    if (threadIdx.x == 0) {
        __hip_atomic_fetch_add(cnt, 1u, __ATOMIC_RELAXED, __HIP_MEMORY_SCOPE_AGENT);
        const unsigned tgt = (*iter + 1u) * GWG;
        while (__hip_atomic_load(cnt, __ATOMIC_RELAXED, __HIP_MEMORY_SCOPE_AGENT) < tgt)
            ;
    }
    ++*iter;
    __syncthreads();
}

// ---------------------------------------------------------------------------
// Dtype sniffer + bars zeroing. emb row 0 is exactly 0.0 by construction:
// bytes [256,512) are zero iff f32 (row 0) and nonzero iff bf16 (row 1).
// ---------------------------------------------------------------------------
__global__ void init_k(const uint32_t* __restrict__ emb_raw,
                       int* __restrict__ flag, unsigned* __restrict__ bars) {
    const int t = threadIdx.x;
    for (int k = t; k < NBARU; k += 1024) bars[k] = 0u;
    if (t == 0) {
        uint32_t acc = 0;
        for (int i = 64; i < 128; ++i) acc |= emb_raw[i];
        *flag = (acc == 0u) ? 0 : 1;
    }
}

// ---------------------------------------------------------------------------
// G[c][j]: input-side gate pre-activations per class. j = q*512 + col,
// q in {0:f, 1:i, 2:o, 3:ctilde}; ctilde quarter pre-sigmoided.
// ---------------------------------------------------------------------------
template <bool BF>
__global__ void build_G(const int* __restrict__ flag,
                        const void* __restrict__ emb,
                        const void* __restrict__ Wfx, const void* __restrict__ Wix,
                        const void* __restrict__ Wox, const void* __restrict__ Wcx,
                        const void* __restrict__ bfv, const void* __restrict__ biv,
                        const void* __restrict__ bov, const void* __restrict__ bcv,
                        float* __restrict__ G) {
    if (*flag != (BF ? 1 : 0)) return;
    const int c   = blockIdx.x;
    const int j   = blockIdx.y * 256 + threadIdx.x;
    const int q   = j >> 9;
    const int col = j & 511;
    const void* W  = (q == 0) ? Wfx : (q == 1) ? Wix : (q == 2) ? Wox : Wcx;
    const void* bv = (q == 0) ? bfv : (q == 1) ? biv : (q == 2) ? bov : bcv;
    float acc = ldv<BF>(bv, col);
    for (int i = 0; i < ID; ++i)
        acc += ldv<BF>(emb, c * ID + i) * ldv<BF>(W, i * HD + col);
    if (q == 3) acc = sigf(acc);
    G[c * 2048 + j] = acc;
}

// ---------------------------------------------------------------------------
// Batch-split recurrence, 32 groups x 8 WGs x 64 cols — r2 structure (512 thr
// x 4 cols x 16 h', agent transport, RMW-IF barrier) with the dot repacked
// for v_pk_fma_f32: weights held as 64 v2f regs (k-pairs, 128 VGPR as
// before), C float4 halves (cv.x,cv.y)/(cv.z,cv.w) are natural VGPR pairs,
// 32 v2f accumulators. FMA issue halves: 512 -> 256 inst/thread/step
// (dot floor ~2048 -> ~1024 cy/SIMD). Accs hold even/odd-k partial sums,
// horizontally added once per step (reassociation only; |delta| ~1e-6 vs
// the 0.131 threshold). Everything else identical to r2.
// ---------------------------------------------------------------------------
template <bool BF>
__global__ __launch_bounds__(THR, 2) void recur_bs(
    const int* __restrict__ flag, const int* __restrict__ x,
    const float* __restrict__ G,
    const void* __restrict__ Wfc, const void* __restrict__ Wic,
    const void* __restrict__ Woc,
    float* __restrict__ C0, float* __restrict__ C1,
    float* __restrict__ Hfb, unsigned* __restrict__ bars)
{
    if (*flag != (BF ? 1 : 0)) return;

    __shared__ __align__(16) float Cs[RPG * CPAD];        // 10.2 KB
    __shared__ __align__(8)  float2 part2[2048 * PST];    // 80 KB
    __shared__ int idx[RPG * TT];                         // 8 KB
    __shared__ int lz[RPG];

    const int blk   = blockIdx.x;
    const int grp   = blk >> 3;           // 0..31
    const int rank  = blk & 7;            // 0..7
    const int r0    = grp * RPG;
    const int h0    = rank * COLS;
    const int tid   = threadIdx.x;
    const int cp    = tid & 15;           // col quad: cols cp, +16, +32, +48
    const int chunk = tid >> 4;           // 0..31 (16 h' each)
    unsigned* bar = bars + grp * 32;      // 128 B apart

    // ---- stage x rows (2048 ints, flat-contiguous), find group start ----
    idx[tid]        = x[r0 * TT + tid];
    idx[tid + 512]  = x[r0 * TT + tid + 512];
    idx[tid + 1024] = x[r0 * TT + tid + 1024];
    idx[tid + 1536] = x[r0 * TT + tid + 1536];
    if (tid < RPG) lz[tid] = -1;
    __syncthreads();
    #pragma unroll
    for (int r = 0; r < RPG; ++r)
        if (idx[r * TT + tid] == 0) atomicMax(&lz[r], tid);
    __syncthreads();
    int t0 = TT;
    #pragma unroll
    for (int r = 0; r < RPG; ++r) t0 = min(t0, lz[r] + 1);
    // t0 is group-uniform: every WG computes it from the same 4 rows.

    // ---- 64 pinned v2f register weights: 4 cols x 2 gates x 8 k-pairs ----
    v2f wpf0[8], wpf1[8], wpf2[8], wpf3[8];
    v2f wpi0[8], wpi1[8], wpi2[8], wpi3[8];
    #pragma unroll
    for (int p = 0; p < 8; ++p) {
        const int hp = chunk * 16 + 2 * p;
        wpf0[p] = (v2f){ldv<BF>(Wfc, hp * HD + h0 + cp),      ldv<BF>(Wfc, (hp+1) * HD + h0 + cp)};
        wpf1[p] = (v2f){ldv<BF>(Wfc, hp * HD + h0 + cp + 16), ldv<BF>(Wfc, (hp+1) * HD + h0 + cp + 16)};
        wpf2[p] = (v2f){ldv<BF>(Wfc, hp * HD + h0 + cp + 32), ldv<BF>(Wfc, (hp+1) * HD + h0 + cp + 32)};
        wpf3[p] = (v2f){ldv<BF>(Wfc, hp * HD + h0 + cp + 48), ldv<BF>(Wfc, (hp+1) * HD + h0 + cp + 48)};
        wpi0[p] = (v2f){ldv<BF>(Wic, hp * HD + h0 + cp),      ldv<BF>(Wic, (hp+1) * HD + h0 + cp)};
        wpi1[p] = (v2f){ldv<BF>(Wic, hp * HD + h0 + cp + 16), ldv<BF>(Wic, (hp+1) * HD + h0 + cp + 16)};
        wpi2[p] = (v2f){ldv<BF>(Wic, hp * HD + h0 + cp + 32), ldv<BF>(Wic, (hp+1) * HD + h0 + cp + 32)};
        wpi3[p] = (v2f){ldv<BF>(Wic, hp * HD + h0 + cp + 48), ldv<BF>(Wic, (hp+1) * HD + h0 + cp + 48)};
    }
    #pragma unroll
    for (int p = 0; p < 8; ++p)
        asm volatile("" : "+v"(wpf0[p]), "+v"(wpf1[p]), "+v"(wpf2[p]), "+v"(wpf3[p]),
                          "+v"(wpi0[p]), "+v"(wpi1[p]), "+v"(wpi2[p]), "+v"(wpi3[p]));

    // ---- zero own C slices in both buffers (coherent stores) ----
    if (tid < COLS * RPG) {
        const int c = tid & 63, r = tid >> 6;
        cst(&C0[(r0 + r) * HD + h0 + c], 0.0f);
        cst(&C1[(r0 + r) * HD + h0 + c], 0.0f);
    }
    unsigned bi = 0;
    gbarrier(bar, &bi);                   // zeros visible group-wide

    float Creg = 0.0f;                    // update threads' own C element
    const bool isUpd = (tid < COLS * RPG);
    const int uc = tid & 63, ur = tid >> 6;   // update thread's (col, row)
    const int pe = cpi(tid);              // padded Cs index of col tid

    for (int t = t0; t < TT; ++t) {
        // re-pin the weights every iteration: forces them to stay VGPR-
        // resident through the loop body (the pre-loop pin alone was not
        // enough in r7/r8/r10 — allocator spilled after the asm point).
        #pragma unroll
        for (int p = 0; p < 8; ++p)
            asm volatile("" : "+v"(wpf0[p]), "+v"(wpf1[p]), "+v"(wpf2[p]), "+v"(wpf3[p]),
                              "+v"(wpi0[p]), "+v"(wpi1[p]), "+v"(wpi2[p]), "+v"(wpi3[p]));

        const float* cur = (t & 1) ? C1 : C0;
        float*       nxt = (t & 1) ? C0 : C1;

        // ---- prefetch G gate operands for the update (overlaps the stage)
        float gf = 0.f, gi = 0.f, sgc = 0.f;
        int cl = 1;
        if (isUpd) {
            cl = idx[ur * TT + t];
            const float* Gr = G + cl * 2048;
            gf  = Gr[h0 + uc];
            gi  = Gr[512 + h0 + uc];
            sgc = Gr[1536 + h0 + uc];
        }

        // ---- stage C(t): all 4 rows at h' = tid ----
        {
            const float v0 = cld(cur + (r0 + 0) * HD + tid);
            const float v1 = cld(cur + (r0 + 1) * HD + tid);
            const float v2 = cld(cur + (r0 + 2) * HD + tid);
            const float v3 = cld(cur + (r0 + 3) * HD + tid);
            Cs[0 * CPAD + pe] = v0;
            Cs[1 * CPAD + pe] = v1;
            Cs[2 * CPAD + pe] = v2;
            Cs[3 * CPAD + pe] = v3;
        }
        __syncthreads();

        // ---- 4-col packed dot over 16 h', all 4 rows ----
        // acc.x sums even k, acc.y odd k; horizontal add after the loop.
        v2f af0[RPG], af1[RPG], af2[RPG], af3[RPG];
        v2f ai0[RPG], ai1[RPG], ai2[RPG], ai3[RPG];
        #pragma unroll
        for (int r = 0; r < RPG; ++r) {
            af0[r] = (v2f)0.f; af1[r] = (v2f)0.f; af2[r] = (v2f)0.f; af3[r] = (v2f)0.f;
            ai0[r] = (v2f)0.f; ai1[r] = (v2f)0.f; ai2[r] = (v2f)0.f; ai3[r] = (v2f)0.f;
        }
        {
            const int cb = chunk * 5;     // float4 index of padded chunk base
            #pragma unroll
            for (int j = 0; j < 4; ++j) {
                #pragma unroll
                for (int r = 0; r < RPG; ++r) {
                    const float4 cv = reinterpret_cast<const float4*>(
                        Cs + r * CPAD)[cb + j];
                    const v2f c01 = (v2f){cv.x, cv.y};
                    const v2f c23 = (v2f){cv.z, cv.w};
                    af0[r] += wpf0[2*j] * c01; af0[r] += wpf0[2*j+1] * c23;
                    af1[r] += wpf1[2*j] * c01; af1[r] += wpf1[2*j+1] * c23;
                    af2[r] += wpf2[2*j] * c01; af2[r] += wpf2[2*j+1] * c23;
                    af3[r] += wpf3[2*j] * c01; af3[r] += wpf3[2*j+1] * c23;
                    ai0[r] += wpi0[2*j] * c01; ai0[r] += wpi0[2*j+1] * c23;
                    ai1[r] += wpi1[2*j] * c01; ai1[r] += wpi1[2*j+1] * c23;
                    ai2[r] += wpi2[2*j] * c01; ai2[r] += wpi2[2*j+1] * c23;
                    ai3[r] += wpi3[2*j] * c01; ai3[r] += wpi3[2*j+1] * c23;
                }
            }
        }
        {
            float2* p0 = part2 + (chunk * 64 + cp)      * PST;
            float2* p1 = part2 + (chunk * 64 + cp + 16) * PST;
            float2* p2 = part2 + (chunk * 64 + cp + 32) * PST;
            float2* p3 = part2 + (chunk * 64 + cp + 48) * PST;
            #pragma unroll
            for (int r = 0; r < RPG; ++r) {
                p0[r] = make_float2(af0[r].x + af0[r].y, ai0[r].x + ai0[r].y);
                p1[r] = make_float2(af1[r].x + af1[r].y, ai1[r].x + ai1[r].y);
                p2[r] = make_float2(af2[r].x + af2[r].y, ai2[r].x + ai2[r].y);
                p3[r] = make_float2(af3[r].x + af3[r].y, ai3[r].x + ai3[r].y);
            }
        }
        __syncthreads();

        // ---- update: thread t<256 owns (col = uc, row = ur) ----
        if (isUpd) {
            float df = 0.f, di = 0.f;
            #pragma unroll
            for (int ch = 0; ch < 32; ++ch) {
                const float2 v = part2[(ch * 64 + uc) * PST + ur];
                df += v.x;
                di += v.y;
            }
            float Cn = sgc * sigf(gi + di) + Creg * sigf(gf + df);
            Cn = (cl > 0) ? Cn : 0.0f;
            Creg = Cn;
            cst(&nxt[(r0 + ur) * HD + h0 + uc], Cn);
        }
        gbarrier(bar, &bi);
    }

    // ---- o-gate + h once. o uses C(T-1) = C1 (pre-update at final step;
    // TT-1 odd -> final input buffer is C1) --
    {
        const float v0 = cld(C1 + (r0 + 0) * HD + tid);
        const float v1 = cld(C1 + (r0 + 1) * HD + tid);
        const float v2 = cld(C1 + (r0 + 2) * HD + tid);
        const float v3 = cld(C1 + (r0 + 3) * HD + tid);
        Cs[0 * CPAD + pe] = v0;
        Cs[1 * CPAD + pe] = v1;
        Cs[2 * CPAD + pe] = v2;
        Cs[3 * CPAD + pe] = v3;
        __syncthreads();

        // thread = (oc = t&63 col, och = t>>6: 8 chunks x 64 h')
        const int oc = tid & 63, och = tid >> 6;
        float ao[RPG];
        #pragma unroll
        for (int r = 0; r < RPG; ++r) ao[r] = 0.0f;
        #pragma unroll 4
        for (int k = 0; k < 64; ++k) {
            const int hp = och * 64 + k;
            const int hpp = cpi(hp);
            const float wo = ldv<BF>(Woc, hp * HD + h0 + oc);
            #pragma unroll
            for (int r = 0; r < RPG; ++r)
                ao[r] += wo * Cs[r * CPAD + hpp];
        }
        {
            float2* pp = part2 + (och * 64 + oc) * PST;
            #pragma unroll
            for (int r2 = 0; r2 < RPG / 2; ++r2)
                pp[r2] = make_float2(ao[2 * r2], ao[2 * r2 + 1]);
        }
        __syncthreads();
        if (isUpd) {
            float s = 0.f;
            #pragma unroll
            for (int ch = 0; ch < 8; ++ch) {
                const float2 v = part2[(ch * 64 + uc) * PST + (ur >> 1)];
                s += (ur & 1) ? v.y : v.x;
            }
            const int cl2 = idx[ur * TT + TT - 1];
            const float o = sigf(G[cl2 * 2048 + 1024 + h0 + uc] + s);
            Hfb[(r0 + ur) * HD + h0 + uc] = tanhf(Creg) * o;
        }
    }
}

// ---------------------------------------------------------------------------
// Projection + log_softmax, one WG per batch row.
// ---------------------------------------------------------------------------
template <bool BF>
__global__ __launch_bounds__(128) void proj(
    const int* __restrict__ flag, const float* __restrict__ Hfb,
    const void* __restrict__ Wph, const void* __restrict__ bp,
    void* __restrict__ out)
{
    if (*flag != (BF ? 1 : 0)) return;
    __shared__ __align__(16) float hv[HD];
    __shared__ float p_s[NCLS];
    __shared__ float lse_s;
    const int b   = blockIdx.x;
    const int tid = threadIdx.x;

    reinterpret_cast<float4*>(hv)[tid] =
        reinterpret_cast<const float4*>(Hfb + b * HD)[tid];
    __syncthreads();

    if (tid < NCLS) {
        float p = ldv<BF>(bp, tid);
        for (int h = 0; h < HD; ++h)
            p += hv[h] * ldv<BF>(Wph, h * NCLS + tid);
        p_s[tid] = p;
    }
    __syncthreads();
    if (tid == 0) {
        float m = -1e30f;
        for (int n = 0; n < NCLS; ++n) m = fmaxf(m, p_s[n]);
        float sum = 0.0f;
        for (int n = 0; n < NCLS; ++n) sum += expf(p_s[n] - m);
        lse_s = m + logf(sum);
    }
    __syncthreads();
    if (tid < NCLS) {
        const float v = p_s[tid] - lse_s;
        if constexpr (BF) ((bf16*)out)[b * NCLS + tid] = __float2bfloat16(v);
        else              ((float*)out)[b * NCLS + tid] = v;
    }
}

// ---------------------------------------------------------------------------
extern "C" void kernel_launch(void* const* d_in, const int* in_sizes, int n_in,
                              void* d_out, int out_size, void* d_ws, size_t ws_size,
                              hipStream_t stream) {
    const int*  x   = (const int*)d_in[0];
    const void* emb = d_in[1];
    const void* Wfx = d_in[2];
    const void* Wfc = d_in[3];
    const void* bfv = d_in[4];
    const void* Wix = d_in[5];
    const void* Wic = d_in[6];
    const void* biv = d_in[7];
    const void* Wox = d_in[8];
    const void* Woc = d_in[9];
    const void* bov = d_in[10];
    const void* Wcx = d_in[11];
    const void* bcv = d_in[12];
    const void* Wph = d_in[13];
    const void* bp  = d_in[14];

    int*      flag = (int*)((char*)d_ws + WS_FLAG);
    unsigned* bars = (unsigned*)((char*)d_ws + WS_BAR);
    float*    G    = (float*)((char*)d_ws + WS_G);
    float*    C0   = (float*)((char*)d_ws + WS_C0);
    float*    C1   = (float*)((char*)d_ws + WS_C1);
    float*    Hfb  = (float*)((char*)d_ws + WS_HFB);

    init_k<<<1, 1024, 0, stream>>>((const uint32_t*)emb, flag, bars);

    build_G<false><<<dim3(NEMB, 8), 256, 0, stream>>>(flag, emb, Wfx, Wix, Wox, Wcx,
                                                      bfv, biv, bov, bcv, G);
    build_G<true ><<<dim3(NEMB, 8), 256, 0, stream>>>(flag, emb, Wfx, Wix, Wox, Wcx,
                                                      bfv, biv, bov, bcv, G);

    {
        void* args[] = {(void*)&flag, (void*)&x, (void*)&G,
                        (void*)&Wfc, (void*)&Wic, (void*)&Woc,
                        (void*)&C0, (void*)&C1, (void*)&Hfb, (void*)&bars};
        hipLaunchCooperativeKernel((const void*)recur_bs<false>, dim3(NGRP * GWG), dim3(THR),
                                   args, 0, stream);
        hipLaunchCooperativeKernel((const void*)recur_bs<true>, dim3(NGRP * GWG), dim3(THR),
                                   args, 0, stream);
    }

    proj<false><<<BB, 128, 0, stream>>>(flag, Hfb, Wph, bp, d_out);
    proj<true ><<<BB, 128, 0, stream>>>(flag, Hfb, Wph, bp, d_out);
}

// Round 6
// 1604.404 us; speedup vs baseline: 1.0192x; 1.0192x over previous
//
#include <hip/hip_runtime.h>
#include <hip/hip_bf16.h>
#include <stdint.h>

#define HD   512   // hidden dim H
#define ID   128   // input dim I
#define NCLS 100   // num classes
#define TT   512   // sequence length T
#define BB   128   // batch B
#define NEMB 101   // NC + 1 embedding rows
#define NGRP 32    // independent batch groups
#define GWG  8     // workgroups per group (sync clique)
#define RPG  4     // batch rows per group
#define COLS 64    // hidden cols per WG (GWG*COLS == HD)
#define THR  512   // threads per recurrence WG (8 waves, 2 waves/SIMD)
#define CPAD 640   // LDS C row stride in floats (f32 path + epilogue)
#define CBW  260   // packed-bf16 C row stride in u32 (256 pairs + 4 pad)
#define PST  5     // partials slot stride in float2 (4 rows + 1 pad)

// workspace layout (bytes)
#define WS_FLAG 0
#define WS_BAR  4096                   // u32 bars[NGRP*32] (128 B apart)
#define WS_G    65536                  // float G[101][2048]  (808 KB)
#define WS_C0   (1u * 1024 * 1024)     // float C0[128][512]  (256 KB)
#define WS_C1   (WS_C0 + 262144)       // float C1[128][512]  (256 KB)
#define WS_HFB  (WS_C1 + 262144)       // float Hfb[128][512] (256 KB)
#define NBARU   4096                   // u32s to zero

using bf16 = __hip_bfloat16;

__device__ __forceinline__ float b2f(bf16 v) { return __bfloat162float(v); }
__device__ __forceinline__ float sigf(float x) { return 1.0f / (1.0f + expf(-x)); }

// Agent-scope accessors — proven r6-r17. Serviced at the die-level coherence
// point: always correct, ~600-900 cy.
// NOTE (r3/r4): sc0 "same-XCD L2" transport is REFUTED on gfx950 — sc0 loads
// hit stale L1 (CU-scope hint, not an L1 bypass). Do not retry sc0.
// NOTE (r5): ext_vector v2f does NOT become v_pk_fma on hipcc (scalarized,
// VALUBusy −8% not −45%) — packed math must be forced via real instructions.
__device__ __forceinline__ float cld(const float* p) {
    return __hip_atomic_load(p, __ATOMIC_RELAXED, __HIP_MEMORY_SCOPE_AGENT);
}
__device__ __forceinline__ void cst(float* p, float v) {
    __hip_atomic_store(p, v, __ATOMIC_RELAXED, __HIP_MEMORY_SCOPE_AGENT);
}
__device__ __forceinline__ uint64_t cld8(const float* p) {
    return __hip_atomic_load((const uint64_t*)p, __ATOMIC_RELAXED,
                             __HIP_MEMORY_SCOPE_AGENT);
}

// pack two f32 into bf16x2 (low = first arg) — gfx950-verified instruction
__device__ __forceinline__ uint32_t pkbf(float x, float y) {
    uint32_t u;
    asm("v_cvt_pk_bf16_f32 %0, %1, %2" : "=v"(u) : "v"(x), "v"(y));
    return u;
}
// 2-way bf16 dot with f32 accumulate (VOP3P, CDNA lineage) — 2 MAC / inst.
// Non-volatile: schedulable by the compiler, ordered by dataflow.
#define DOT2(acc, w, c) \
    asm("v_dot2_f32_bf16 %0, %1, %2, %0" : "+v"(acc) : "v"(w), "v"(c))

template <bool BF>
__device__ __forceinline__ float ldv(const void* p, int i) {
    if constexpr (BF) return b2f(((const bf16*)p)[i]);
    else              return ((const float*)p)[i];
}

// padded f32 Cs index for h' (16 data floats + 4 pad per chunk)
__device__ __forceinline__ int cpi(int h) { return (h >> 4) * 20 + (h & 15); }

// ---------------------------------------------------------------------------
// Group barrier — r13's best-measured flavor (RMW-IF + tight poll). Leading
// __syncthreads drains all waves' sc1 C stores before the arrive.
// ---------------------------------------------------------------------------
__device__ __forceinline__ void gbarrier(unsigned* cnt, unsigned* iter) {
    __syncthreads();
    if (threadIdx.x == 0) {
        __hip_atomic_fetch_add(cnt, 1u, __ATOMIC_RELAXED, __HIP_MEMORY_SCOPE_AGENT);
        const unsigned tgt = (*iter + 1u) * GWG;
        while (__hip_atomic_load(cnt, __ATOMIC_RELAXED, __HIP_MEMORY_SCOPE_AGENT) < tgt)
            ;
    }
    ++*iter;
    __syncthreads();
}

// ---------------------------------------------------------------------------
// Dtype sniffer + bars zeroing. emb row 0 is exactly 0.0 by construction:
// bytes [256,512) are zero iff f32 (row 0) and nonzero iff bf16 (row 1).
// ---------------------------------------------------------------------------
__global__ void init_k(const uint32_t* __restrict__ emb_raw,
                       int* __restrict__ flag, unsigned* __restrict__ bars) {
    const int t = threadIdx.x;
    for (int k = t; k < NBARU; k += 1024) bars[k] = 0u;
    if (t == 0) {
        uint32_t acc = 0;
        for (int i = 64; i < 128; ++i) acc |= emb_raw[i];
        *flag = (acc == 0u) ? 0 : 1;
    }
}

// ---------------------------------------------------------------------------
// G[c][j]: input-side gate pre-activations per class. j = q*512 + col,
// q in {0:f, 1:i, 2:o, 3:ctilde}; ctilde quarter pre-sigmoided.
// ---------------------------------------------------------------------------
template <bool BF>
__global__ void build_G(const int* __restrict__ flag,
                        const void* __restrict__ emb,
                        const void* __restrict__ Wfx, const void* __restrict__ Wix,
                        const void* __restrict__ Wox, const void* __restrict__ Wcx,
                        const void* __restrict__ bfv, const void* __restrict__ biv,
                        const void* __restrict__ bov, const void* __restrict__ bcv,
                        float* __restrict__ G) {
    if (*flag != (BF ? 1 : 0)) return;
    const int c   = blockIdx.x;
    const int j   = blockIdx.y * 256 + threadIdx.x;
    const int q   = j >> 9;
    const int col = j & 511;
    const void* W  = (q == 0) ? Wfx : (q == 1) ? Wix : (q == 2) ? Wox : Wcx;
    const void* bv = (q == 0) ? bfv : (q == 1) ? biv : (q == 2) ? bov : bcv;
    float acc = ldv<BF>(bv, col);
    for (int i = 0; i < ID; ++i)
        acc += ldv<BF>(emb, c * ID + i) * ldv<BF>(W, i * HD + col);
    if (q == 3) acc = sigf(acc);
    G[c * 2048 + j] = acc;
}

// ---------------------------------------------------------------------------
// Batch-split recurrence, 32 groups x 8 WGs x 64 cols — r2 sync structure
// (agent transport, RMW-IF barrier). BF=true (the live path: test data IS
// bf16) uses a bf16-native dot:
//   - weights as packed bf16 h'-pairs: 64 u32 regs/thread (raw bf16 bits,
//     exact since inputs are bf16);
//   - stage: 2x 8B agent loads/thread (was 4x 4B), v_cvt_pk_bf16_f32 to
//     bf16x2, ds_write_b32 into packed C tile [4][CBW];
//   - dot: 256 v_dot2_f32_bf16/thread (was 512 v_fma) + 8 b128 LDS reads
//     (was 16). Dot issue 2048 -> 1024 cy/SIMD, LDS 1536 -> 768 cy.
//   - update stays f32 (C published f32; only the dot operand is rounded).
// BF=false keeps the exact r2 f32 path (proven; dead at runtime for this
// test's data but must stay correct).
// ---------------------------------------------------------------------------
template <bool BF>
__global__ __launch_bounds__(THR, 2) void recur_bs(
    const int* __restrict__ flag, const int* __restrict__ x,
    const float* __restrict__ G,
    const void* __restrict__ Wfc, const void* __restrict__ Wic,
    const void* __restrict__ Woc,
    float* __restrict__ C0, float* __restrict__ C1,
    float* __restrict__ Hfb, unsigned* __restrict__ bars)
{
    if (*flag != (BF ? 1 : 0)) return;

    __shared__ __align__(16) float Cs[RPG * CPAD];        // 10.2 KB (aliased by packed tile)
    __shared__ __align__(8)  float2 part2[2048 * PST];    // 80 KB
    __shared__ int idx[RPG * TT];                         // 8 KB
    __shared__ int lz[RPG];

    const int blk   = blockIdx.x;
    const int grp   = blk >> 3;           // 0..31
    const int rank  = blk & 7;            // 0..7
    const int r0    = grp * RPG;
    const int h0    = rank * COLS;
    const int tid   = threadIdx.x;
    const int cp    = tid & 15;           // col quad: cols cp, +16, +32, +48
    const int chunk = tid >> 4;           // 0..31 (16 h' each)
    unsigned* bar = bars + grp * 32;      // 128 B apart

    // ---- stage x rows (2048 ints, flat-contiguous), find group start ----
    idx[tid]        = x[r0 * TT + tid];
    idx[tid + 512]  = x[r0 * TT + tid + 512];
    idx[tid + 1024] = x[r0 * TT + tid + 1024];
    idx[tid + 1536] = x[r0 * TT + tid + 1536];
    if (tid < RPG) lz[tid] = -1;
    __syncthreads();
    #pragma unroll
    for (int r = 0; r < RPG; ++r)
        if (idx[r * TT + tid] == 0) atomicMax(&lz[r], tid);
    __syncthreads();
    int t0 = TT;
    #pragma unroll
    for (int r = 0; r < RPG; ++r) t0 = min(t0, lz[r] + 1);
    // t0 is group-uniform: every WG computes it from the same 4 rows.

    unsigned bi = 0;
    float Creg = 0.0f;                    // update threads' own C element
    const bool isUpd = (tid < COLS * RPG);
    const int uc = tid & 63, ur = tid >> 6;   // update thread's (col, row)
    const int pe = cpi(tid);              // padded f32 Cs index of col tid

    if constexpr (BF) {
        // ================== bf16-native dot path (live) ===================
        const uint16_t* Wfr = (const uint16_t*)Wfc;
        const uint16_t* Wir = (const uint16_t*)Wic;

        // 64 packed weight regs: 4 cols x 2 gates x 8 h'-pairs
        uint32_t wf0[8], wf1[8], wf2[8], wf3[8];
        uint32_t wi0[8], wi1[8], wi2[8], wi3[8];
        #pragma unroll
        for (int p = 0; p < 8; ++p) {
            const int hp = chunk * 16 + 2 * p;
            const int b0 = hp * HD + h0 + cp, b1 = (hp + 1) * HD + h0 + cp;
            wf0[p] = (uint32_t)Wfr[b0]      | ((uint32_t)Wfr[b1]      << 16);
            wf1[p] = (uint32_t)Wfr[b0 + 16] | ((uint32_t)Wfr[b1 + 16] << 16);
            wf2[p] = (uint32_t)Wfr[b0 + 32] | ((uint32_t)Wfr[b1 + 32] << 16);
            wf3[p] = (uint32_t)Wfr[b0 + 48] | ((uint32_t)Wfr[b1 + 48] << 16);
            wi0[p] = (uint32_t)Wir[b0]      | ((uint32_t)Wir[b1]      << 16);
            wi1[p] = (uint32_t)Wir[b0 + 16] | ((uint32_t)Wir[b1 + 16] << 16);
            wi2[p] = (uint32_t)Wir[b0 + 32] | ((uint32_t)Wir[b1 + 32] << 16);
            wi3[p] = (uint32_t)Wir[b0 + 48] | ((uint32_t)Wir[b1 + 48] << 16);
        }
        #pragma unroll
        for (int p = 0; p < 8; ++p)
            asm volatile("" : "+v"(wf0[p]), "+v"(wf1[p]), "+v"(wf2[p]), "+v"(wf3[p]),
                              "+v"(wi0[p]), "+v"(wi1[p]), "+v"(wi2[p]), "+v"(wi3[p]));

        // zero own C slices in both buffers
        if (isUpd) {
            cst(&C0[(r0 + ur) * HD + h0 + uc], 0.0f);
            cst(&C1[(r0 + ur) * HD + h0 + uc], 0.0f);
        }
        gbarrier(bar, &bi);               // zeros visible group-wide

        uint32_t* Cb = (uint32_t*)Cs;     // packed tile [RPG][CBW] (4.2 KB)
        const int srow = tid >> 8;        // 0..1 (rows srow, srow+2)
        const int spr  = tid & 255;       // h'-pair index

        for (int t = t0; t < TT; ++t) {
            // re-pin weights every iteration (r7/r8/r10 lesson)
            #pragma unroll
            for (int p = 0; p < 8; ++p)
                asm volatile("" : "+v"(wf0[p]), "+v"(wf1[p]), "+v"(wf2[p]), "+v"(wf3[p]),
                                  "+v"(wi0[p]), "+v"(wi1[p]), "+v"(wi2[p]), "+v"(wi3[p]));

            const float* cur = (t & 1) ? C1 : C0;
            float*       nxt = (t & 1) ? C0 : C1;

            // ---- prefetch G gate operands (overlaps the stage) ----
            float gf = 0.f, gi = 0.f, sgc = 0.f;
            int cl = 1;
            if (isUpd) {
                cl = idx[ur * TT + t];
                const float* Gr = G + cl * 2048;
                gf  = Gr[h0 + uc];
                gi  = Gr[512 + h0 + uc];
                sgc = Gr[1536 + h0 + uc];
            }

            // ---- stage C(t): two 8B agent loads -> bf16x2 pack -> LDS ----
            {
                const uint64_t a = cld8(cur + (r0 + srow) * HD + 2 * spr);
                const uint64_t b = cld8(cur + (r0 + srow + 2) * HD + 2 * spr);
                const uint32_t pa = pkbf(__uint_as_float((uint32_t)a),
                                         __uint_as_float((uint32_t)(a >> 32)));
                const uint32_t pb = pkbf(__uint_as_float((uint32_t)b),
                                         __uint_as_float((uint32_t)(b >> 32)));
                Cb[srow * CBW + spr]       = pa;
                Cb[(srow + 2) * CBW + spr] = pb;
            }
            __syncthreads();

            // ---- 4-col packed dot over 16 h' (8 pairs), all 4 rows ----
            float f0[RPG], f1[RPG], f2[RPG], f3[RPG];
            float i0[RPG], i1[RPG], i2[RPG], i3[RPG];
            #pragma unroll
            for (int r = 0; r < RPG; ++r) {
                f0[r] = 0.f; f1[r] = 0.f; f2[r] = 0.f; f3[r] = 0.f;
                i0[r] = 0.f; i1[r] = 0.f; i2[r] = 0.f; i3[r] = 0.f;
            }
            {
                const int cb = chunk * 8;     // word index of chunk base
                #pragma unroll
                for (int hh = 0; hh < 2; ++hh) {
                    #pragma unroll
                    for (int r = 0; r < RPG; ++r) {
                        const uint4 cv = *reinterpret_cast<const uint4*>(
                            Cb + r * CBW + cb + 4 * hh);
                        const int p = 4 * hh;
                        DOT2(f0[r], wf0[p + 0], cv.x); DOT2(f0[r], wf0[p + 1], cv.y);
                        DOT2(f0[r], wf0[p + 2], cv.z); DOT2(f0[r], wf0[p + 3], cv.w);
                        DOT2(f1[r], wf1[p + 0], cv.x); DOT2(f1[r], wf1[p + 1], cv.y);
                        DOT2(f1[r], wf1[p + 2], cv.z); DOT2(f1[r], wf1[p + 3], cv.w);
                        DOT2(f2[r], wf2[p + 0], cv.x); DOT2(f2[r], wf2[p + 1], cv.y);
                        DOT2(f2[r], wf2[p + 2], cv.z); DOT2(f2[r], wf2[p + 3], cv.w);
                        DOT2(f3[r], wf3[p + 0], cv.x); DOT2(f3[r], wf3[p + 1], cv.y);
                        DOT2(f3[r], wf3[p + 2], cv.z); DOT2(f3[r], wf3[p + 3], cv.w);
                        DOT2(i0[r], wi0[p + 0], cv.x); DOT2(i0[r], wi0[p + 1], cv.y);
                        DOT2(i0[r], wi0[p + 2], cv.z); DOT2(i0[r], wi0[p + 3], cv.w);
                        DOT2(i1[r], wi1[p + 0], cv.x); DOT2(i1[r], wi1[p + 1], cv.y);
                        DOT2(i1[r], wi1[p + 2], cv.z); DOT2(i1[r], wi1[p + 3], cv.w);
                        DOT2(i2[r], wi2[p + 0], cv.x); DOT2(i2[r], wi2[p + 1], cv.y);
                        DOT2(i2[r], wi2[p + 2], cv.z); DOT2(i2[r], wi2[p + 3], cv.w);
                        DOT2(i3[r], wi3[p + 0], cv.x); DOT2(i3[r], wi3[p + 1], cv.y);
                        DOT2(i3[r], wi3[p + 2], cv.z); DOT2(i3[r], wi3[p + 3], cv.w);
                    }
                }
            }
            {
                float2* p0 = part2 + (chunk * 64 + cp)      * PST;
                float2* p1 = part2 + (chunk * 64 + cp + 16) * PST;
                float2* p2 = part2 + (chunk * 64 + cp + 32) * PST;
                float2* p3 = part2 + (chunk * 64 + cp + 48) * PST;
                #pragma unroll
                for (int r = 0; r < RPG; ++r) {
                    p0[r] = make_float2(f0[r], i0[r]);
                    p1[r] = make_float2(f1[r], i1[r]);
                    p2[r] = make_float2(f2[r], i2[r]);
                    p3[r] = make_float2(f3[r], i3[r]);
                }
            }
            __syncthreads();

            // ---- update: thread t<256 owns (col = uc, row = ur) ----
            if (isUpd) {
                float df = 0.f, di = 0.f;
                #pragma unroll
                for (int ch = 0; ch < 32; ++ch) {
                    const float2 v = part2[(ch * 64 + uc) * PST + ur];
                    df += v.x;
                    di += v.y;
                }
                float Cn = sgc * sigf(gi + di) + Creg * sigf(gf + df);
                Cn = (cl > 0) ? Cn : 0.0f;
                Creg = Cn;
                cst(&nxt[(r0 + ur) * HD + h0 + uc], Cn);
            }
            gbarrier(bar, &bi);
        }
    } else {
        // ================== exact r2 f32 path (proven) ====================
        float wf0[16], wf1[16], wf2[16], wf3[16];
        float wi0[16], wi1[16], wi2[16], wi3[16];
        #pragma unroll
        for (int k = 0; k < 16; ++k) {
            const int hp = chunk * 16 + k;
            wf0[k] = ldv<BF>(Wfc, hp * HD + h0 + cp);
            wf1[k] = ldv<BF>(Wfc, hp * HD + h0 + cp + 16);
            wf2[k] = ldv<BF>(Wfc, hp * HD + h0 + cp + 32);
            wf3[k] = ldv<BF>(Wfc, hp * HD + h0 + cp + 48);
            wi0[k] = ldv<BF>(Wic, hp * HD + h0 + cp);
            wi1[k] = ldv<BF>(Wic, hp * HD + h0 + cp + 16);
            wi2[k] = ldv<BF>(Wic, hp * HD + h0 + cp + 32);
            wi3[k] = ldv<BF>(Wic, hp * HD + h0 + cp + 48);
        }
        #pragma unroll
        for (int k = 0; k < 16; ++k)
            asm volatile("" : "+v"(wf0[k]), "+v"(wf1[k]), "+v"(wf2[k]), "+v"(wf3[k]),
                              "+v"(wi0[k]), "+v"(wi1[k]), "+v"(wi2[k]), "+v"(wi3[k]));

        if (isUpd) {
            cst(&C0[(r0 + ur) * HD + h0 + uc], 0.0f);
            cst(&C1[(r0 + ur) * HD + h0 + uc], 0.0f);
        }
        gbarrier(bar, &bi);

        for (int t = t0; t < TT; ++t) {
            #pragma unroll
            for (int k = 0; k < 16; ++k)
                asm volatile("" : "+v"(wf0[k]), "+v"(wf1[k]), "+v"(wf2[k]), "+v"(wf3[k]),
                                  "+v"(wi0[k]), "+v"(wi1[k]), "+v"(wi2[k]), "+v"(wi3[k]));

            const float* cur = (t & 1) ? C1 : C0;
            float*       nxt = (t & 1) ? C0 : C1;

            float gf = 0.f, gi = 0.f, sgc = 0.f;
            int cl = 1;
            if (isUpd) {
                cl = idx[ur * TT + t];
                const float* Gr = G + cl * 2048;
                gf  = Gr[h0 + uc];
                gi  = Gr[512 + h0 + uc];
                sgc = Gr[1536 + h0 + uc];
            }

            {
                const float v0 = cld(cur + (r0 + 0) * HD + tid);
                const float v1 = cld(cur + (r0 + 1) * HD + tid);
                const float v2 = cld(cur + (r0 + 2) * HD + tid);
                const float v3 = cld(cur + (r0 + 3) * HD + tid);
                Cs[0 * CPAD + pe] = v0;
                Cs[1 * CPAD + pe] = v1;
                Cs[2 * CPAD + pe] = v2;
                Cs[3 * CPAD + pe] = v3;
            }
            __syncthreads();

            float f0[RPG], f1[RPG], f2[RPG], f3[RPG];
            float i0[RPG], i1[RPG], i2[RPG], i3[RPG];
            #pragma unroll
            for (int r = 0; r < RPG; ++r) {
                f0[r] = 0.f; f1[r] = 0.f; f2[r] = 0.f; f3[r] = 0.f;
                i0[r] = 0.f; i1[r] = 0.f; i2[r] = 0.f; i3[r] = 0.f;
            }
            {
                const int cb = chunk * 5;
                #pragma unroll
                for (int j = 0; j < 4; ++j) {
                    #pragma unroll
                    for (int r = 0; r < RPG; ++r) {
                        const float4 cv = reinterpret_cast<const float4*>(
                            Cs + r * CPAD)[cb + j];
                        f0[r] += wf0[4*j]*cv.x + wf0[4*j+1]*cv.y + wf0[4*j+2]*cv.z + wf0[4*j+3]*cv.w;
                        f1[r] += wf1[4*j]*cv.x + wf1[4*j+1]*cv.y + wf1[4*j+2]*cv.z + wf1[4*j+3]*cv.w;
                        f2[r] += wf2[4*j]*cv.x + wf2[4*j+1]*cv.y + wf2[4*j+2]*cv.z + wf2[4*j+3]*cv.w;
                        f3[r] += wf3[4*j]*cv.x + wf3[4*j+1]*cv.y + wf3[4*j+2]*cv.z + wf3[4*j+3]*cv.w;
                        i0[r] += wi0[4*j]*cv.x + wi0[4*j+1]*cv.y + wi0[4*j+2]*cv.z + wi0[4*j+3]*cv.w;
                        i1[r] += wi1[4*j]*cv.x + wi1[4*j+1]*cv.y + wi1[4*j+2]*cv.z + wi1[4*j+3]*cv.w;
                        i2[r] += wi2[4*j]*cv.x + wi2[4*j+1]*cv.y + wi2[4*j+2]*cv.z + wi2[4*j+3]*cv.w;
                        i3[r] += wi3[4*j]*cv.x + wi3[4*j+1]*cv.y + wi3[4*j+2]*cv.z + wi3[4*j+3]*cv.w;
                    }
                }
            }
            {
                float2* p0 = part2 + (chunk * 64 + cp)      * PST;
                float2* p1 = part2 + (chunk * 64 + cp + 16) * PST;
                float2* p2 = part2 + (chunk * 64 + cp + 32) * PST;
                float2* p3 = part2 + (chunk * 64 + cp + 48) * PST;
                #pragma unroll
                for (int r = 0; r < RPG; ++r) {
                    p0[r] = make_float2(f0[r], i0[r]);
                    p1[r] = make_float2(f1[r], i1[r]);
                    p2[r] = make_float2(f2[r], i2[r]);
                    p3[r] = make_float2(f3[r], i3[r]);
                }
            }
            __syncthreads();

            if (isUpd) {
                float df = 0.f, di = 0.f;
                #pragma unroll
                for (int ch = 0; ch < 32; ++ch) {
                    const float2 v = part2[(ch * 64 + uc) * PST + ur];
                    df += v.x;
                    di += v.y;
                }
                float Cn = sgc * sigf(gi + di) + Creg * sigf(gf + df);
                Cn = (cl > 0) ? Cn : 0.0f;
                Creg = Cn;
                cst(&nxt[(r0 + ur) * HD + h0 + uc], Cn);
            }
            gbarrier(bar, &bi);
        }
    }

    // ---- o-gate + h once (f32, both paths). o uses C(T-1) = C1 (pre-update
    // at final step; TT-1 odd -> final input buffer is C1) --
    {
        const float v0 = cld(C1 + (r0 + 0) * HD + tid);
        const float v1 = cld(C1 + (r0 + 1) * HD + tid);
        const float v2 = cld(C1 + (r0 + 2) * HD + tid);
        const float v3 = cld(C1 + (r0 + 3) * HD + tid);
        Cs[0 * CPAD + pe] = v0;
        Cs[1 * CPAD + pe] = v1;
        Cs[2 * CPAD + pe] = v2;
        Cs[3 * CPAD + pe] = v3;
        __syncthreads();

        // thread = (oc = t&63 col, och = t>>6: 8 chunks x 64 h')
        const int oc = tid & 63, och = tid >> 6;
        float ao[RPG];
        #pragma unroll
        for (int r = 0; r < RPG; ++r) ao[r] = 0.0f;
        #pragma unroll 4
        for (int k = 0; k < 64; ++k) {
            const int hp = och * 64 + k;
            const int hpp = cpi(hp);
            const float wo = ldv<BF>(Woc, hp * HD + h0 + oc);
            #pragma unroll
            for (int r = 0; r < RPG; ++r)
                ao[r] += wo * Cs[r * CPAD + hpp];
        }
        {
            float2* pp = part2 + (och * 64 + oc) * PST;
            #pragma unroll
            for (int r2 = 0; r2 < RPG / 2; ++r2)
                pp[r2] = make_float2(ao[2 * r2], ao[2 * r2 + 1]);
        }
        __syncthreads();
        if (isUpd) {
            float s = 0.f;
            #pragma unroll
            for (int ch = 0; ch < 8; ++ch) {
                const float2 v = part2[(ch * 64 + uc) * PST + (ur >> 1)];
                s += (ur & 1) ? v.y : v.x;
            }
            const int cl2 = idx[ur * TT + TT - 1];
            const float o = sigf(G[cl2 * 2048 + 1024 + h0 + uc] + s);
            Hfb[(r0 + ur) * HD + h0 + uc] = tanhf(Creg) * o;
        }
    }
}

// ---------------------------------------------------------------------------
// Projection + log_softmax, one WG per batch row.
// ---------------------------------------------------------------------------
template <bool BF>
__global__ __launch_bounds__(128) void proj(
    const int* __restrict__ flag, const float* __restrict__ Hfb,
    const void* __restrict__ Wph, const void* __restrict__ bp,
    void* __restrict__ out)
{
    if (*flag != (BF ? 1 : 0)) return;
    __shared__ __align__(16) float hv[HD];
    __shared__ float p_s[NCLS];
    __shared__ float lse_s;
    const int b   = blockIdx.x;
    const int tid = threadIdx.x;

    reinterpret_cast<float4*>(hv)[tid] =
        reinterpret_cast<const float4*>(Hfb + b * HD)[tid];
    __syncthreads();

    if (tid < NCLS) {
        float p = ldv<BF>(bp, tid);
        for (int h = 0; h < HD; ++h)
            p += hv[h] * ldv<BF>(Wph, h * NCLS + tid);
        p_s[tid] = p;
    }
    __syncthreads();
    if (tid == 0) {
        float m = -1e30f;
        for (int n = 0; n < NCLS; ++n) m = fmaxf(m, p_s[n]);
        float sum = 0.0f;
        for (int n = 0; n < NCLS; ++n) sum += expf(p_s[n] - m);
        lse_s = m + logf(sum);
    }
    __syncthreads();
    if (tid < NCLS) {
        const float v = p_s[tid] - lse_s;
        if constexpr (BF) ((bf16*)out)[b * NCLS + tid] = __float2bfloat16(v);
        else              ((float*)out)[b * NCLS + tid] = v;
    }
}

// ---------------------------------------------------------------------------
extern "C" void kernel_launch(void* const* d_in, const int* in_sizes, int n_in,
                              void* d_out, int out_size, void* d_ws, size_t ws_size,
                              hipStream_t stream) {
    const int*  x   = (const int*)d_in[0];
    const void* emb = d_in[1];
    const void* Wfx = d_in[2];
    const void* Wfc = d_in[3];
    const void* bfv = d_in[4];
    const void* Wix = d_in[5];
    const void* Wic = d_in[6];
    const void* biv = d_in[7];
    const void* Wox = d_in[8];
    const void* Woc = d_in[9];
    const void* bov = d_in[10];
    const void* Wcx = d_in[11];
    const void* bcv = d_in[12];
    const void* Wph = d_in[13];
    const void* bp  = d_in[14];

    int*      flag = (int*)((char*)d_ws + WS_FLAG);
    unsigned* bars = (unsigned*)((char*)d_ws + WS_BAR);
    float*    G    = (float*)((char*)d_ws + WS_G);
    float*    C0   = (float*)((char*)d_ws + WS_C0);
    float*    C1   = (float*)((char*)d_ws + WS_C1);
    float*    Hfb  = (float*)((char*)d_ws + WS_HFB);

    init_k<<<1, 1024, 0, stream>>>((const uint32_t*)emb, flag, bars);

    build_G<false><<<dim3(NEMB, 8), 256, 0, stream>>>(flag, emb, Wfx, Wix, Wox, Wcx,
                                                      bfv, biv, bov, bcv, G);
    build_G<true ><<<dim3(NEMB, 8), 256, 0, stream>>>(flag, emb, Wfx, Wix, Wox, Wcx,
                                                      bfv, biv, bov, bcv, G);

    {
        void* args[] = {(void*)&flag, (void*)&x, (void*)&G,
                        (void*)&Wfc, (void*)&Wic, (void*)&Woc,
                        (void*)&C0, (void*)&C1, (void*)&Hfb, (void*)&bars};
        hipLaunchCooperativeKernel((const void*)recur_bs<false>, dim3(NGRP * GWG), dim3(THR),
                                   args, 0, stream);
        hipLaunchCooperativeKernel((const void*)recur_bs<true>, dim3(NGRP * GWG), dim3(THR),
                                   args, 0, stream);
    }

    proj<false><<<BB, 128, 0, stream>>>(flag, Hfb, Wph, bp, d_out);
    proj<true ><<<BB, 128, 0, stream>>>(flag, Hfb, Wph, bp, d_out);
}

// Round 7
// 1598.781 us; speedup vs baseline: 1.0228x; 1.0035x over previous
//
#include <hip/hip_runtime.h>
#include <hip/hip_bf16.h>
#include <stdint.h>

#define HD   512   // hidden dim H
#define ID   128   // input dim I
#define NCLS 100   // num classes
#define TT   512   // sequence length T
#define BB   128   // batch B
#define NEMB 101   // NC + 1 embedding rows
#define THR  512   // threads per recurrence WG (8 waves, 2 waves/SIMD)

// bf16 (live) geometry: 64 groups x 4-WG clique x 128 cols, 2 rows/group.
// RPG*COLS = 256 is factorization-invariant -> same per-thread compute as
// the 8-clique, but: 4 barrier arrivals (was 8), half the stage volume,
// half the partial-reduce, and E[max-of-N] straggler skew at N=4 not 8.
#define NGRPB 64
#define GWGB  4
#define RPGB  2
#define COLSB 128
// f32 (fallback) geometry: r2-proven 32 x 8 x 64, 4 rows/group (dead for
// this test's bf16 data; kept verbatim for correctness).
#define NGRPF 32
#define GWGF  8
#define RPGF  4
#define COLSF 64

#define CPAD 640   // f32 LDS C row stride (32 chunks x (16 data + 4 pad))
#define CBW  260   // packed-bf16 C row stride in u32 (256 pairs + 4 pad)
#define PSTF 5     // f32-path partials stride in float2 (4 rows + 1 pad)
#define PSTB 3     // bf16-path partials stride in float2 (2 rows + 1 pad)

// workspace layout (bytes)
#define WS_FLAG 0
#define WS_BAR  4096                   // u32 bars[NGRP*32] (128 B apart)
#define WS_G    65536                  // float G[101][2048]  (808 KB)
#define WS_C0   (1u * 1024 * 1024)     // float C0[128][512]  (256 KB)
#define WS_C1   (WS_C0 + 262144)       // float C1[128][512]  (256 KB)
#define WS_HFB  (WS_C1 + 262144)       // float Hfb[128][512] (256 KB)
#define NBARU   4096                   // u32s to zero

using bf16 = __hip_bfloat16;

__device__ __forceinline__ float b2f(bf16 v) { return __bfloat162float(v); }
__device__ __forceinline__ float sigf(float x) { return 1.0f / (1.0f + expf(-x)); }

// Agent-scope accessors — proven r6-r17 (die-level coherence point; always
// correct, ~600-900 cy).
// LEDGER of refuted alternatives:
//  r1: per-rank ready-flag exchange — publish chain longer than central RMW.
//  r3/r4: sc0 same-XCD L2 transport — sc0 loads hit stale L1 (CU-scope
//         hint, not L1 bypass); deterministic corruption. Do not retry.
//  r5: ext_vector v2f — hipcc scalarizes; packed math needs real instrs.
//  r6: dot2+LDS halving — ZERO dur change: compute is off the critical
//      path; the step is exchange-latency/skew-bound.
__device__ __forceinline__ float cld(const float* p) {
    return __hip_atomic_load(p, __ATOMIC_RELAXED, __HIP_MEMORY_SCOPE_AGENT);
}
__device__ __forceinline__ void cst(float* p, float v) {
    __hip_atomic_store(p, v, __ATOMIC_RELAXED, __HIP_MEMORY_SCOPE_AGENT);
}
__device__ __forceinline__ uint64_t cld8(const float* p) {
    return __hip_atomic_load((const uint64_t*)p, __ATOMIC_RELAXED,
                             __HIP_MEMORY_SCOPE_AGENT);
}

// pack two f32 into bf16x2 (low = first arg) — gfx950-verified instruction
__device__ __forceinline__ uint32_t pkbf(float x, float y) {
    uint32_t u;
    asm("v_cvt_pk_bf16_f32 %0, %1, %2" : "=v"(u) : "v"(x), "v"(y));
    return u;
}
// 2-way bf16 dot with f32 accumulate (VOP3P) — 2 MAC / inst, schedulable.
#define DOT2(acc, w, c) \
    asm("v_dot2_f32_bf16 %0, %1, %2, %0" : "+v"(acc) : "v"(w), "v"(c))

template <bool BF>
__device__ __forceinline__ float ldv(const void* p, int i) {
    if constexpr (BF) return b2f(((const bf16*)p)[i]);
    else              return ((const float*)p)[i];
}

// padded f32 Cs index for h' (16 data floats + 4 pad per chunk)
__device__ __forceinline__ int cpi(int h) { return (h >> 4) * 20 + (h & 15); }

// ---------------------------------------------------------------------------
// Group barrier — r13's best-measured flavor (RMW-IF + tight poll). Leading
// __syncthreads drains all waves' sc1 C stores before the arrive. gwg is a
// compile-time constant per instantiation.
// ---------------------------------------------------------------------------
__device__ __forceinline__ void gbarrier(unsigned* cnt, unsigned* iter, int gwg) {
    __syncthreads();
    if (threadIdx.x == 0) {
        __hip_atomic_fetch_add(cnt, 1u, __ATOMIC_RELAXED, __HIP_MEMORY_SCOPE_AGENT);
        const unsigned tgt = (*iter + 1u) * (unsigned)gwg;
        while (__hip_atomic_load(cnt, __ATOMIC_RELAXED, __HIP_MEMORY_SCOPE_AGENT) < tgt)
            ;
    }
    ++*iter;
    __syncthreads();
}

// ---------------------------------------------------------------------------
// Dtype sniffer + bars zeroing. emb row 0 is exactly 0.0 by construction:
// bytes [256,512) are zero iff f32 (row 0) and nonzero iff bf16 (row 1).
// ---------------------------------------------------------------------------
__global__ void init_k(const uint32_t* __restrict__ emb_raw,
                       int* __restrict__ flag, unsigned* __restrict__ bars) {
    const int t = threadIdx.x;
    for (int k = t; k < NBARU; k += 1024) bars[k] = 0u;
    if (t == 0) {
        uint32_t acc = 0;
        for (int i = 64; i < 128; ++i) acc |= emb_raw[i];
        *flag = (acc == 0u) ? 0 : 1;
    }
}

// ---------------------------------------------------------------------------
// G[c][j]: input-side gate pre-activations per class. j = q*512 + col,
// q in {0:f, 1:i, 2:o, 3:ctilde}; ctilde quarter pre-sigmoided.
// ---------------------------------------------------------------------------
template <bool BF>
__global__ void build_G(const int* __restrict__ flag,
                        const void* __restrict__ emb,
                        const void* __restrict__ Wfx, const void* __restrict__ Wix,
                        const void* __restrict__ Wox, const void* __restrict__ Wcx,
                        const void* __restrict__ bfv, const void* __restrict__ biv,
                        const void* __restrict__ bov, const void* __restrict__ bcv,
                        float* __restrict__ G) {
    if (*flag != (BF ? 1 : 0)) return;
    const int c   = blockIdx.x;
    const int j   = blockIdx.y * 256 + threadIdx.x;
    const int q   = j >> 9;
    const int col = j & 511;
    const void* W  = (q == 0) ? Wfx : (q == 1) ? Wix : (q == 2) ? Wox : Wcx;
    const void* bv = (q == 0) ? bfv : (q == 1) ? biv : (q == 2) ? bov : bcv;
    float acc = ldv<BF>(bv, col);
    for (int i = 0; i < ID; ++i)
        acc += ldv<BF>(emb, c * ID + i) * ldv<BF>(W, i * HD + col);
    if (q == 3) acc = sigf(acc);
    G[c * 2048 + j] = acc;
}

// ---------------------------------------------------------------------------
// Batch-split recurrence. BF=true (live): 64 groups x 4-WG clique x 128 cols,
// 2 rows/group, bf16 dot (r6 machinery re-factored to the small clique):
//   - 128 packed-bf16 weight u32 regs/thread (4 cols x 2 gates x 16 pairs);
//   - stage: ONE 8B agent load/thread -> pkbf -> one ds_write;
//   - dot: 8 b128 LDS reads + 256 v_dot2_f32_bf16 (unchanged vs r6);
//   - partials: 8 float2 writes; update reduce: 16 float2 reads (was 32);
//   - barrier: 4 arrivals (was 8).
// BF=false: exact r2 f32 path at the proven 32x8x64 geometry.
// ---------------------------------------------------------------------------
template <bool BF>
__global__ __launch_bounds__(THR, 2) void recur_bs(
    const int* __restrict__ flag, const int* __restrict__ x,
    const float* __restrict__ G,
    const void* __restrict__ Wfc, const void* __restrict__ Wic,
    const void* __restrict__ Woc,
    float* __restrict__ C0, float* __restrict__ C1,
    float* __restrict__ Hfb, unsigned* __restrict__ bars)
{
    if (*flag != (BF ? 1 : 0)) return;

    __shared__ __align__(16) float Cs[RPGF * CPAD];       // 10.2 KB (max of paths)
    __shared__ __align__(8)  float2 part2[2048 * PSTF];   // 80 KB
    __shared__ int idx[RPGF * TT];                        // 8 KB
    __shared__ int lz[RPGF];

    const int blk = blockIdx.x;
    const int tid = threadIdx.x;
    unsigned bi = 0;

    if constexpr (BF) {
        // ================= bf16 path: 4-WG clique (live) ==================
        const int grp   = blk >> 2;       // 0..63
        const int rank  = blk & 3;        // 0..3
        const int r0    = grp * RPGB;
        const int h0    = rank * COLSB;
        const int cp    = tid & 31;       // cols cp, +32, +64, +96
        const int chunk = tid >> 5;       // 0..15 (32 h' each)
        unsigned* bar = bars + grp * 32;  // 128 B apart

        // ---- stage x rows (1024 ints), find group start ----
        idx[tid]       = x[r0 * TT + tid];
        idx[tid + 512] = x[r0 * TT + tid + 512];
        if (tid < RPGB) lz[tid] = -1;
        __syncthreads();
        #pragma unroll
        for (int r = 0; r < RPGB; ++r)
            if (idx[r * TT + tid] == 0) atomicMax(&lz[r], tid);
        __syncthreads();
        int t0 = TT;
        #pragma unroll
        for (int r = 0; r < RPGB; ++r) t0 = min(t0, lz[r] + 1);
        // t0 is group-uniform (computed from the same rows by all 4 WGs).

        // ---- 128 packed weight regs: 4 cols x 2 gates x 16 h'-pairs ----
        const uint16_t* Wfr = (const uint16_t*)Wfc;
        const uint16_t* Wir = (const uint16_t*)Wic;
        uint32_t wf0[16], wf1[16], wf2[16], wf3[16];
        uint32_t wi0[16], wi1[16], wi2[16], wi3[16];
        #pragma unroll
        for (int p = 0; p < 16; ++p) {
            const int hp = chunk * 32 + 2 * p;
            const int b0 = hp * HD + h0 + cp, b1 = (hp + 1) * HD + h0 + cp;
            wf0[p] = (uint32_t)Wfr[b0]      | ((uint32_t)Wfr[b1]      << 16);
            wf1[p] = (uint32_t)Wfr[b0 + 32] | ((uint32_t)Wfr[b1 + 32] << 16);
            wf2[p] = (uint32_t)Wfr[b0 + 64] | ((uint32_t)Wfr[b1 + 64] << 16);
            wf3[p] = (uint32_t)Wfr[b0 + 96] | ((uint32_t)Wfr[b1 + 96] << 16);
            wi0[p] = (uint32_t)Wir[b0]      | ((uint32_t)Wir[b1]      << 16);
            wi1[p] = (uint32_t)Wir[b0 + 32] | ((uint32_t)Wir[b1 + 32] << 16);
            wi2[p] = (uint32_t)Wir[b0 + 64] | ((uint32_t)Wir[b1 + 64] << 16);
            wi3[p] = (uint32_t)Wir[b0 + 96] | ((uint32_t)Wir[b1 + 96] << 16);
        }
        #pragma unroll
        for (int p = 0; p < 16; ++p)
            asm volatile("" : "+v"(wf0[p]), "+v"(wf1[p]), "+v"(wf2[p]), "+v"(wf3[p]),
                              "+v"(wi0[p]), "+v"(wi1[p]), "+v"(wi2[p]), "+v"(wi3[p]));

        const bool isUpd = (tid < COLSB * RPGB);      // 256 update threads
        const int uc = tid & 127, ur = tid >> 7;      // (col, row)

        // ---- zero own C slices in both buffers ----
        if (isUpd) {
            cst(&C0[(r0 + ur) * HD + h0 + uc], 0.0f);
            cst(&C1[(r0 + ur) * HD + h0 + uc], 0.0f);
        }
        gbarrier(bar, &bi, GWGB);         // zeros visible group-wide

        float Creg = 0.0f;
        uint32_t* Cb = (uint32_t*)Cs;     // packed tile [RPGB][CBW]
        const int srow = tid >> 8;        // 0..1
        const int spr  = tid & 255;       // h'-pair index

        for (int t = t0; t < TT; ++t) {
            // re-pin weights every iteration (r7/r8/r10 lesson)
            #pragma unroll
            for (int p = 0; p < 16; ++p)
                asm volatile("" : "+v"(wf0[p]), "+v"(wf1[p]), "+v"(wf2[p]), "+v"(wf3[p]),
                                  "+v"(wi0[p]), "+v"(wi1[p]), "+v"(wi2[p]), "+v"(wi3[p]));

            const float* cur = (t & 1) ? C1 : C0;
            float*       nxt = (t & 1) ? C0 : C1;

            // ---- prefetch G gate operands (overlaps the stage) ----
            float gf = 0.f, gi = 0.f, sgc = 0.f;
            int cl = 1;
            if (isUpd) {
                cl = idx[ur * TT + t];
                const float* Gr = G + cl * 2048;
                gf  = Gr[h0 + uc];
                gi  = Gr[512 + h0 + uc];
                sgc = Gr[1536 + h0 + uc];
            }

            // ---- stage C(t): ONE 8B agent load -> bf16x2 -> LDS ----
            {
                const uint64_t a = cld8(cur + (r0 + srow) * HD + 2 * spr);
                Cb[srow * CBW + spr] = pkbf(__uint_as_float((uint32_t)a),
                                            __uint_as_float((uint32_t)(a >> 32)));
            }
            __syncthreads();

            // ---- 4-col packed dot over 32 h' (16 pairs), both rows ----
            float f0[RPGB], f1[RPGB], f2[RPGB], f3[RPGB];
            float i0[RPGB], i1[RPGB], i2[RPGB], i3[RPGB];
            #pragma unroll
            for (int r = 0; r < RPGB; ++r) {
                f0[r] = 0.f; f1[r] = 0.f; f2[r] = 0.f; f3[r] = 0.f;
                i0[r] = 0.f; i1[r] = 0.f; i2[r] = 0.f; i3[r] = 0.f;
            }
            {
                const int cb = chunk * 16;    // u32 word base of the chunk
                #pragma unroll
                for (int hh = 0; hh < 4; ++hh) {
                    #pragma unroll
                    for (int r = 0; r < RPGB; ++r) {
                        const uint4 cv = *reinterpret_cast<const uint4*>(
                            Cb + r * CBW + cb + 4 * hh);
                        const int p = 4 * hh;
                        DOT2(f0[r], wf0[p + 0], cv.x); DOT2(f0[r], wf0[p + 1], cv.y);
                        DOT2(f0[r], wf0[p + 2], cv.z); DOT2(f0[r], wf0[p + 3], cv.w);
                        DOT2(f1[r], wf1[p + 0], cv.x); DOT2(f1[r], wf1[p + 1], cv.y);
                        DOT2(f1[r], wf1[p + 2], cv.z); DOT2(f1[r], wf1[p + 3], cv.w);
                        DOT2(f2[r], wf2[p + 0], cv.x); DOT2(f2[r], wf2[p + 1], cv.y);
                        DOT2(f2[r], wf2[p + 2], cv.z); DOT2(f2[r], wf2[p + 3], cv.w);
                        DOT2(f3[r], wf3[p + 0], cv.x); DOT2(f3[r], wf3[p + 1], cv.y);
                        DOT2(f3[r], wf3[p + 2], cv.z); DOT2(f3[r], wf3[p + 3], cv.w);
                        DOT2(i0[r], wi0[p + 0], cv.x); DOT2(i0[r], wi0[p + 1], cv.y);
                        DOT2(i0[r], wi0[p + 2], cv.z); DOT2(i0[r], wi0[p + 3], cv.w);
                        DOT2(i1[r], wi1[p + 0], cv.x); DOT2(i1[r], wi1[p + 1], cv.y);
                        DOT2(i1[r], wi1[p + 2], cv.z); DOT2(i1[r], wi1[p + 3], cv.w);
                        DOT2(i2[r], wi2[p + 0], cv.x); DOT2(i2[r], wi2[p + 1], cv.y);
                        DOT2(i2[r], wi2[p + 2], cv.z); DOT2(i2[r], wi2[p + 3], cv.w);
                        DOT2(i3[r], wi3[p + 0], cv.x); DOT2(i3[r], wi3[p + 1], cv.y);
                        DOT2(i3[r], wi3[p + 2], cv.z); DOT2(i3[r], wi3[p + 3], cv.w);
                    }
                }
            }
            {
                float2* p0 = part2 + (chunk * 128 + cp)      * PSTB;
                float2* p1 = part2 + (chunk * 128 + cp + 32) * PSTB;
                float2* p2 = part2 + (chunk * 128 + cp + 64) * PSTB;
                float2* p3 = part2 + (chunk * 128 + cp + 96) * PSTB;
                #pragma unroll
                for (int r = 0; r < RPGB; ++r) {
                    p0[r] = make_float2(f0[r], i0[r]);
                    p1[r] = make_float2(f1[r], i1[r]);
                    p2[r] = make_float2(f2[r], i2[r]);
                    p3[r] = make_float2(f3[r], i3[r]);
                }
            }
            __syncthreads();

            // ---- update: thread t<256 owns (col = uc, row = ur) ----
            if (isUpd) {
                float df = 0.f, di = 0.f;
                #pragma unroll
                for (int ch = 0; ch < 16; ++ch) {
                    const float2 v = part2[(ch * 128 + uc) * PSTB + ur];
                    df += v.x;
                    di += v.y;
                }
                float Cn = sgc * sigf(gi + di) + Creg * sigf(gf + df);
                Cn = (cl > 0) ? Cn : 0.0f;
                Creg = Cn;
                cst(&nxt[(r0 + ur) * HD + h0 + uc], Cn);
            }
            gbarrier(bar, &bi, GWGB);
        }

        // ---- o-gate + h. o uses C(T-1) = C1 (pre-update at final step) ----
        {
            const float v0 = cld(C1 + (r0 + 0) * HD + tid);
            const float v1 = cld(C1 + (r0 + 1) * HD + tid);
            const int pe = cpi(tid);
            Cs[0 * CPAD + pe] = v0;
            Cs[1 * CPAD + pe] = v1;
            __syncthreads();

            // thread = (oc = tid&127 col, och = tid>>7: 4 chunks x 128 h')
            const int oc = tid & 127, och = tid >> 7;
            float ao0 = 0.f, ao1 = 0.f;
            #pragma unroll 4
            for (int k = 0; k < 128; ++k) {
                const int hp  = och * 128 + k;
                const int hpp = cpi(hp);
                const float wo = ldv<BF>(Woc, hp * HD + h0 + oc);
                ao0 += wo * Cs[0 * CPAD + hpp];
                ao1 += wo * Cs[1 * CPAD + hpp];
            }
            part2[(och * 128 + oc) * PSTB] = make_float2(ao0, ao1);
            __syncthreads();
            if (isUpd) {
                float s = 0.f;
                #pragma unroll
                for (int ch = 0; ch < 4; ++ch) {
                    const float2 v = part2[(ch * 128 + uc) * PSTB];
                    s += ur ? v.y : v.x;
                }
                const int cl2 = idx[ur * TT + TT - 1];
                const float o = sigf(G[cl2 * 2048 + 1024 + h0 + uc] + s);
                Hfb[(r0 + ur) * HD + h0 + uc] = tanhf(Creg) * o;
            }
        }
    } else {
        // ============ f32 path: r2-proven 8-WG clique (fallback) ==========
        const int grp   = blk >> 3;       // 0..31
        const int rank  = blk & 7;        // 0..7
        const int r0    = grp * RPGF;
        const int h0    = rank * COLSF;
        const int cp    = tid & 15;       // cols cp, +16, +32, +48
        const int chunk = tid >> 4;       // 0..31 (16 h' each)
        unsigned* bar = bars + grp * 32;

        idx[tid]        = x[r0 * TT + tid];
        idx[tid + 512]  = x[r0 * TT + tid + 512];
        idx[tid + 1024] = x[r0 * TT + tid + 1024];
        idx[tid + 1536] = x[r0 * TT + tid + 1536];
        if (tid < RPGF) lz[tid] = -1;
        __syncthreads();
        #pragma unroll
        for (int r = 0; r < RPGF; ++r)
            if (idx[r * TT + tid] == 0) atomicMax(&lz[r], tid);
        __syncthreads();
        int t0 = TT;
        #pragma unroll
        for (int r = 0; r < RPGF; ++r) t0 = min(t0, lz[r] + 1);

        float wf0[16], wf1[16], wf2[16], wf3[16];
        float wi0[16], wi1[16], wi2[16], wi3[16];
        #pragma unroll
        for (int k = 0; k < 16; ++k) {
            const int hp = chunk * 16 + k;
            wf0[k] = ldv<BF>(Wfc, hp * HD + h0 + cp);
            wf1[k] = ldv<BF>(Wfc, hp * HD + h0 + cp + 16);
            wf2[k] = ldv<BF>(Wfc, hp * HD + h0 + cp + 32);
            wf3[k] = ldv<BF>(Wfc, hp * HD + h0 + cp + 48);
            wi0[k] = ldv<BF>(Wic, hp * HD + h0 + cp);
            wi1[k] = ldv<BF>(Wic, hp * HD + h0 + cp + 16);
            wi2[k] = ldv<BF>(Wic, hp * HD + h0 + cp + 32);
            wi3[k] = ldv<BF>(Wic, hp * HD + h0 + cp + 48);
        }
        #pragma unroll
        for (int k = 0; k < 16; ++k)
            asm volatile("" : "+v"(wf0[k]), "+v"(wf1[k]), "+v"(wf2[k]), "+v"(wf3[k]),
                              "+v"(wi0[k]), "+v"(wi1[k]), "+v"(wi2[k]), "+v"(wi3[k]));

        const bool isUpd = (tid < COLSF * RPGF);
        const int uc = tid & 63, ur = tid >> 6;
        const int pe = cpi(tid);

        if (isUpd) {
            cst(&C0[(r0 + ur) * HD + h0 + uc], 0.0f);
            cst(&C1[(r0 + ur) * HD + h0 + uc], 0.0f);
        }
        gbarrier(bar, &bi, GWGF);

        float Creg = 0.0f;
        for (int t = t0; t < TT; ++t) {
            #pragma unroll
            for (int k = 0; k < 16; ++k)
                asm volatile("" : "+v"(wf0[k]), "+v"(wf1[k]), "+v"(wf2[k]), "+v"(wf3[k]),
                                  "+v"(wi0[k]), "+v"(wi1[k]), "+v"(wi2[k]), "+v"(wi3[k]));

            const float* cur = (t & 1) ? C1 : C0;
            float*       nxt = (t & 1) ? C0 : C1;

            float gf = 0.f, gi = 0.f, sgc = 0.f;
            int cl = 1;
            if (isUpd) {
                cl = idx[ur * TT + t];
                const float* Gr = G + cl * 2048;
                gf  = Gr[h0 + uc];
                gi  = Gr[512 + h0 + uc];
                sgc = Gr[1536 + h0 + uc];
            }

            {
                const float v0 = cld(cur + (r0 + 0) * HD + tid);
                const float v1 = cld(cur + (r0 + 1) * HD + tid);
                const float v2 = cld(cur + (r0 + 2) * HD + tid);
                const float v3 = cld(cur + (r0 + 3) * HD + tid);
                Cs[0 * CPAD + pe] = v0;
                Cs[1 * CPAD + pe] = v1;
                Cs[2 * CPAD + pe] = v2;
                Cs[3 * CPAD + pe] = v3;
            }
            __syncthreads();

            float f0[RPGF], f1[RPGF], f2[RPGF], f3[RPGF];
            float i0[RPGF], i1[RPGF], i2[RPGF], i3[RPGF];
            #pragma unroll
            for (int r = 0; r < RPGF; ++r) {
                f0[r] = 0.f; f1[r] = 0.f; f2[r] = 0.f; f3[r] = 0.f;
                i0[r] = 0.f; i1[r] = 0.f; i2[r] = 0.f; i3[r] = 0.f;
            }
            {
                const int cb = chunk * 5;
                #pragma unroll
                for (int j = 0; j < 4; ++j) {
                    #pragma unroll
                    for (int r = 0; r < RPGF; ++r) {
                        const float4 cv = reinterpret_cast<const float4*>(
                            Cs + r * CPAD)[cb + j];
                        f0[r] += wf0[4*j]*cv.x + wf0[4*j+1]*cv.y + wf0[4*j+2]*cv.z + wf0[4*j+3]*cv.w;
                        f1[r] += wf1[4*j]*cv.x + wf1[4*j+1]*cv.y + wf1[4*j+2]*cv.z + wf1[4*j+3]*cv.w;
                        f2[r] += wf2[4*j]*cv.x + wf2[4*j+1]*cv.y + wf2[4*j+2]*cv.z + wf2[4*j+3]*cv.w;
                        f3[r] += wf3[4*j]*cv.x + wf3[4*j+1]*cv.y + wf3[4*j+2]*cv.z + wf3[4*j+3]*cv.w;
                        i0[r] += wi0[4*j]*cv.x + wi0[4*j+1]*cv.y + wi0[4*j+2]*cv.z + wi0[4*j+3]*cv.w;
                        i1[r] += wi1[4*j]*cv.x + wi1[4*j+1]*cv.y + wi1[4*j+2]*cv.z + wi1[4*j+3]*cv.w;
                        i2[r] += wi2[4*j]*cv.x + wi2[4*j+1]*cv.y + wi2[4*j+2]*cv.z + wi2[4*j+3]*cv.w;
                        i3[r] += wi3[4*j]*cv.x + wi3[4*j+1]*cv.y + wi3[4*j+2]*cv.z + wi3[4*j+3]*cv.w;
                    }
                }
            }
            {
                float2* p0 = part2 + (chunk * 64 + cp)      * PSTF;
                float2* p1 = part2 + (chunk * 64 + cp + 16) * PSTF;
                float2* p2 = part2 + (chunk * 64 + cp + 32) * PSTF;
                float2* p3 = part2 + (chunk * 64 + cp + 48) * PSTF;
                #pragma unroll
                for (int r = 0; r < RPGF; ++r) {
                    p0[r] = make_float2(f0[r], i0[r]);
                    p1[r] = make_float2(f1[r], i1[r]);
                    p2[r] = make_float2(f2[r], i2[r]);
                    p3[r] = make_float2(f3[r], i3[r]);
                }
            }
            __syncthreads();

            if (isUpd) {
                float df = 0.f, di = 0.f;
                #pragma unroll
                for (int ch = 0; ch < 32; ++ch) {
                    const float2 v = part2[(ch * 64 + uc) * PSTF + ur];
                    df += v.x;
                    di += v.y;
                }
                float Cn = sgc * sigf(gi + di) + Creg * sigf(gf + df);
                Cn = (cl > 0) ? Cn : 0.0f;
                Creg = Cn;
                cst(&nxt[(r0 + ur) * HD + h0 + uc], Cn);
            }
            gbarrier(bar, &bi, GWGF);
        }

        // ---- o-gate + h (r2 epilogue) ----
        {
            const float v0 = cld(C1 + (r0 + 0) * HD + tid);
            const float v1 = cld(C1 + (r0 + 1) * HD + tid);
            const float v2 = cld(C1 + (r0 + 2) * HD + tid);
            const float v3 = cld(C1 + (r0 + 3) * HD + tid);
            Cs[0 * CPAD + pe] = v0;
            Cs[1 * CPAD + pe] = v1;
            Cs[2 * CPAD + pe] = v2;
            Cs[3 * CPAD + pe] = v3;
            __syncthreads();

            const int oc = tid & 63, och = tid >> 6;
            float ao[RPGF];
            #pragma unroll
            for (int r = 0; r < RPGF; ++r) ao[r] = 0.0f;
            #pragma unroll 4
            for (int k = 0; k < 64; ++k) {
                const int hp = och * 64 + k;
                const int hpp = cpi(hp);
                const float wo = ldv<BF>(Woc, hp * HD + h0 + oc);
                #pragma unroll
                for (int r = 0; r < RPGF; ++r)
                    ao[r] += wo * Cs[r * CPAD + hpp];
            }
            {
                float2* pp = part2 + (och * 64 + oc) * PSTF;
                #pragma unroll
                for (int r2 = 0; r2 < RPGF / 2; ++r2)
                    pp[r2] = make_float2(ao[2 * r2], ao[2 * r2 + 1]);
            }
            __syncthreads();
            if (isUpd) {
                float s = 0.f;
                #pragma unroll
                for (int ch = 0; ch < 8; ++ch) {
                    const float2 v = part2[(ch * 64 + uc) * PSTF + (ur >> 1)];
                    s += (ur & 1) ? v.y : v.x;
                }
                const int cl2 = idx[ur * TT + TT - 1];
                const float o = sigf(G[cl2 * 2048 + 1024 + h0 + uc] + s);
                Hfb[(r0 + ur) * HD + h0 + uc] = tanhf(Creg) * o;
            }
        }
    }
}

// ---------------------------------------------------------------------------
// Projection + log_softmax, one WG per batch row.
// ---------------------------------------------------------------------------
template <bool BF>
__global__ __launch_bounds__(128) void proj(
    const int* __restrict__ flag, const float* __restrict__ Hfb,
    const void* __restrict__ Wph, const void* __restrict__ bp,
    void* __restrict__ out)
{
    if (*flag != (BF ? 1 : 0)) return;
    __shared__ __align__(16) float hv[HD];
    __shared__ float p_s[NCLS];
    __shared__ float lse_s;
    const int b   = blockIdx.x;
    const int tid = threadIdx.x;

    reinterpret_cast<float4*>(hv)[tid] =
        reinterpret_cast<const float4*>(Hfb + b * HD)[tid];
    __syncthreads();

    if (tid < NCLS) {
        float p = ldv<BF>(bp, tid);
        for (int h = 0; h < HD; ++h)
            p += hv[h] * ldv<BF>(Wph, h * NCLS + tid);
        p_s[tid] = p;
    }
    __syncthreads();
    if (tid == 0) {
        float m = -1e30f;
        for (int n = 0; n < NCLS; ++n) m = fmaxf(m, p_s[n]);
        float sum = 0.0f;
        for (int n = 0; n < NCLS; ++n) sum += expf(p_s[n] - m);
        lse_s = m + logf(sum);
    }
    __syncthreads();
    if (tid < NCLS) {
        const float v = p_s[tid] - lse_s;
        if constexpr (BF) ((bf16*)out)[b * NCLS + tid] = __float2bfloat16(v);
        else              ((float*)out)[b * NCLS + tid] = v;
    }
}

// ---------------------------------------------------------------------------
extern "C" void kernel_launch(void* const* d_in, const int* in_sizes, int n_in,
                              void* d_out, int out_size, void* d_ws, size_t ws_size,
                              hipStream_t stream) {
    const int*  x   = (const int*)d_in[0];
    const void* emb = d_in[1];
    const void* Wfx = d_in[2];
    const void* Wfc = d_in[3];
    const void* bfv = d_in[4];
    const void* Wix = d_in[5];
    const void* Wic = d_in[6];
    const void* biv = d_in[7];
    const void* Wox = d_in[8];
    const void* Woc = d_in[9];
    const void* bov = d_in[10];
    const void* Wcx = d_in[11];
    const void* bcv = d_in[12];
    const void* Wph = d_in[13];
    const void* bp  = d_in[14];

    int*      flag = (int*)((char*)d_ws + WS_FLAG);
    unsigned* bars = (unsigned*)((char*)d_ws + WS_BAR);
    float*    G    = (float*)((char*)d_ws + WS_G);
    float*    C0   = (float*)((char*)d_ws + WS_C0);
    float*    C1   = (float*)((char*)d_ws + WS_C1);
    float*    Hfb  = (float*)((char*)d_ws + WS_HFB);

    init_k<<<1, 1024, 0, stream>>>((const uint32_t*)emb, flag, bars);

    build_G<false><<<dim3(NEMB, 8), 256, 0, stream>>>(flag, emb, Wfx, Wix, Wox, Wcx,
                                                      bfv, biv, bov, bcv, G);
    build_G<true ><<<dim3(NEMB, 8), 256, 0, stream>>>(flag, emb, Wfx, Wix, Wox, Wcx,
                                                      bfv, biv, bov, bcv, G);

    {
        // 256 blocks either way: bf16 path reads blk as 64x4, f32 as 32x8.
        void* args[] = {(void*)&flag, (void*)&x, (void*)&G,
                        (void*)&Wfc, (void*)&Wic, (void*)&Woc,
                        (void*)&C0, (void*)&C1, (void*)&Hfb, (void*)&bars};
        hipLaunchCooperativeKernel((const void*)recur_bs<false>, dim3(256), dim3(THR),
                                   args, 0, stream);
        hipLaunchCooperativeKernel((const void*)recur_bs<true>, dim3(256), dim3(THR),
                                   args, 0, stream);
    }

    proj<false><<<BB, 128, 0, stream>>>(flag, Hfb, Wph, bp, d_out);
    proj<true ><<<BB, 128, 0, stream>>>(flag, Hfb, Wph, bp, d_out);
}

// Round 8
// 1593.229 us; speedup vs baseline: 1.0264x; 1.0035x over previous
//
#include <hip/hip_runtime.h>
#include <hip/hip_bf16.h>
#include <stdint.h>

#define HD   512   // hidden dim H
#define ID   128   // input dim I
#define NCLS 100   // num classes
#define TT   512   // sequence length T
#define BB   128   // batch B
#define NEMB 101   // NC + 1 embedding rows
#define THR  512   // threads per recurrence WG (8 waves, 2 waves/SIMD)

// bf16 (live) geometry: 64 groups x 4-WG clique x 128 cols, 2 rows/group.
#define NGRPB 64
#define GWGB  4
#define RPGB  2
#define COLSB 128
// f32 (fallback) geometry: r2-proven 32 x 8 x 64 (dead for bf16 data).
#define NGRPF 32
#define GWGF  8
#define RPGF  4
#define COLSF 64

#define CPAD 640   // f32 LDS C row stride (32 chunks x (16 data + 4 pad))
#define CBW  260   // packed-bf16 C row stride in u32 (256 pairs + 4 pad)
#define PSTF 5     // f32-path partials stride in float2
#define PSTB 3     // bf16-path partials stride in float2

// workspace layout (bytes)
#define WS_FLAG 0
#define WS_BAR  4096                   // u32 bars[NGRP*32] (f32 path only)
#define WS_G    65536                  // float G[101][2048]  (808 KB)
#define WS_C0   (1u * 1024 * 1024)     // C0[128][512]: f32 (f32 path) or tagged u32 (bf16 path)
#define WS_C1   (WS_C0 + 262144)
#define WS_HFB  (WS_C1 + 262144)       // float Hfb[128][512] (256 KB)
#define NBARU   4096
#define NCU     65536                  // u32s per C buffer

using bf16 = __hip_bfloat16;

__device__ __forceinline__ float b2f(bf16 v) { return __bfloat162float(v); }
__device__ __forceinline__ float sigf(float x) { return 1.0f / (1.0f + expf(-x)); }

// Agent-scope accessors — proven r6-r17 (die-level coherence point).
// LEDGER of refuted alternatives:
//  r1: per-rank ready-flag exchange — flag+data as SEPARATE words = 3 serial
//      legs; lost to the central barrier.
//  r3/r4: sc0 same-XCD L2 transport — sc0 loads hit stale L1. Do not retry.
//  r5: ext_vector v2f — hipcc scalarizes.
//  r6: dot2+LDS halving — null: compute off the critical path.
//  r7: clique 8->4, stage/reduce halved — null: the step is the FIXED
//      latency chain (publish-ack, RMW, poll, load), not throughput.
// r8 (this round): TAGGED DATAFLOW — tag rides IN the data word
//      (bf16<<16|step): consumer spin-load IS poll+publish-ack+load in one
//      leg; central barrier deleted. Anti-dependency proof: B publishes t+1
//      only after fully staging C(t) (syncs order stage->dot->update); A
//      overwrites buf[t&1] with t+2 only after observing ALL t+1 tags =>
//      every rank consumed C(t). Skew bounded at 1 step; '==' spin safe.
__device__ __forceinline__ float cld(const float* p) {
    return __hip_atomic_load(p, __ATOMIC_RELAXED, __HIP_MEMORY_SCOPE_AGENT);
}
__device__ __forceinline__ void cst(float* p, float v) {
    __hip_atomic_store(p, v, __ATOMIC_RELAXED, __HIP_MEMORY_SCOPE_AGENT);
}
__device__ __forceinline__ void cstu(uint32_t* p, uint32_t v) {
    __hip_atomic_store(p, v, __ATOMIC_RELAXED, __HIP_MEMORY_SCOPE_AGENT);
}
__device__ __forceinline__ uint64_t cldu8(const uint64_t* p) {
    return __hip_atomic_load(p, __ATOMIC_RELAXED, __HIP_MEMORY_SCOPE_AGENT);
}

// pack two f32 into bf16x2 (low = first arg) — gfx950-verified instruction
__device__ __forceinline__ uint32_t pkbf(float x, float y) {
    uint32_t u;
    asm("v_cvt_pk_bf16_f32 %0, %1, %2" : "=v"(u) : "v"(x), "v"(y));
    return u;
}
// 2-way bf16 dot with f32 accumulate (VOP3P) — schedulable.
#define DOT2(acc, w, c) \
    asm("v_dot2_f32_bf16 %0, %1, %2, %0" : "+v"(acc) : "v"(w), "v"(c))

template <bool BF>
__device__ __forceinline__ float ldv(const void* p, int i) {
    if constexpr (BF) return b2f(((const bf16*)p)[i]);
    else              return ((const float*)p)[i];
}

// padded f32 Cs index for h' (16 data floats + 4 pad per chunk)
__device__ __forceinline__ int cpi(int h) { return (h >> 4) * 20 + (h & 15); }

// ---------------------------------------------------------------------------
// Group barrier — r13 flavor; f32 fallback path only.
// ---------------------------------------------------------------------------
__device__ __forceinline__ void gbarrier(unsigned* cnt, unsigned* iter, int gwg) {
    __syncthreads();
    if (threadIdx.x == 0) {
        __hip_atomic_fetch_add(cnt, 1u, __ATOMIC_RELAXED, __HIP_MEMORY_SCOPE_AGENT);
        const unsigned tgt = (*iter + 1u) * (unsigned)gwg;
        while (__hip_atomic_load(cnt, __ATOMIC_RELAXED, __HIP_MEMORY_SCOPE_AGENT) < tgt)
            ;
    }
    ++*iter;
    __syncthreads();
}

// ---------------------------------------------------------------------------
// Dtype sniffer + bars + FULL C-buffer zeroing (kills stale step-tags from
// prior graph replays — mandatory for the tagged-dataflow exchange).
// ---------------------------------------------------------------------------
__global__ void init_k(const uint32_t* __restrict__ emb_raw,
                       int* __restrict__ flag, unsigned* __restrict__ bars,
                       uint32_t* __restrict__ c0, uint32_t* __restrict__ c1) {
    const int t = blockIdx.x * 1024 + threadIdx.x;
    for (int k = t; k < NBARU; k += 8192) bars[k] = 0u;
    for (int k = t; k < NCU; k += 8192) { c0[k] = 0u; c1[k] = 0u; }
    if (t == 0) {
        uint32_t acc = 0;
        for (int i = 64; i < 128; ++i) acc |= emb_raw[i];
        *flag = (acc == 0u) ? 0 : 1;
    }
}

// ---------------------------------------------------------------------------
// G[c][j]: input-side gate pre-activations per class. j = q*512 + col,
// q in {0:f, 1:i, 2:o, 3:ctilde}; ctilde quarter pre-sigmoided.
// ---------------------------------------------------------------------------
template <bool BF>
__global__ void build_G(const int* __restrict__ flag,
                        const void* __restrict__ emb,
                        const void* __restrict__ Wfx, const void* __restrict__ Wix,
                        const void* __restrict__ Wox, const void* __restrict__ Wcx,
                        const void* __restrict__ bfv, const void* __restrict__ biv,
                        const void* __restrict__ bov, const void* __restrict__ bcv,
                        float* __restrict__ G) {
    if (*flag != (BF ? 1 : 0)) return;
    const int c   = blockIdx.x;
    const int j   = blockIdx.y * 256 + threadIdx.x;
    const int q   = j >> 9;
    const int col = j & 511;
    const void* W  = (q == 0) ? Wfx : (q == 1) ? Wix : (q == 2) ? Wox : Wcx;
    const void* bv = (q == 0) ? bfv : (q == 1) ? biv : (q == 2) ? bov : bcv;
    float acc = ldv<BF>(bv, col);
    for (int i = 0; i < ID; ++i)
        acc += ldv<BF>(emb, c * ID + i) * ldv<BF>(W, i * HD + col);
    if (q == 3) acc = sigf(acc);
    G[c * 2048 + j] = acc;
}

// ---------------------------------------------------------------------------
// Batch-split recurrence. BF=true (live): 64 groups x 4-WG clique x 128 cols,
// 2 rows/group, bf16 dot, TAGGED-DATAFLOW exchange (no barrier):
//   publish: u32 = bf16(Cn)<<16 | (t+1); stage: b64 spin-load until both
//   tags == t, pack the two bf16 into one LDS word. Ping-pong C0/C1 keeps
//   the 1-step-skew anti-dependency (proof in ledger above). Epilogue reads
//   C(T-1) straight from the LDS tile (staged at the final iteration).
// BF=false: exact r2 f32 path at the proven 32x8x64 geometry + barrier.
// ---------------------------------------------------------------------------
template <bool BF>
__global__ __launch_bounds__(THR, 2) void recur_bs(
    const int* __restrict__ flag, const int* __restrict__ x,
    const float* __restrict__ G,
    const void* __restrict__ Wfc, const void* __restrict__ Wic,
    const void* __restrict__ Woc,
    float* __restrict__ C0, float* __restrict__ C1,
    float* __restrict__ Hfb, unsigned* __restrict__ bars)
{
    if (*flag != (BF ? 1 : 0)) return;

    __shared__ __align__(16) float Cs[RPGF * CPAD];       // 10.2 KB
    __shared__ __align__(16) uint32_t CbS[RPGB * CBW];    // 2.1 KB packed tile
    __shared__ __align__(8)  float2 part2[2048 * PSTF];   // 80 KB
    __shared__ int idx[RPGF * TT];                        // 8 KB
    __shared__ int lz[RPGF];

    const int blk = blockIdx.x;
    const int tid = threadIdx.x;
    unsigned bi = 0;

    if constexpr (BF) {
        // ============== bf16 path: tagged dataflow (live) =================
        const int grp   = blk >> 2;       // 0..63
        const int rank  = blk & 3;        // 0..3
        const int r0    = grp * RPGB;
        const int h0    = rank * COLSB;
        const int cp    = tid & 31;       // cols cp, +32, +64, +96
        const int chunk = tid >> 5;       // 0..15 (32 h' each)

        // ---- stage x rows (1024 ints), zero CbS, find group start ----
        idx[tid]       = x[r0 * TT + tid];
        idx[tid + 512] = x[r0 * TT + tid + 512];
        for (int k = tid; k < RPGB * CBW; k += THR) CbS[k] = 0u;
        if (tid < RPGB) lz[tid] = -1;
        __syncthreads();
        #pragma unroll
        for (int r = 0; r < RPGB; ++r)
            if (idx[r * TT + tid] == 0) atomicMax(&lz[r], tid);
        __syncthreads();
        int t0 = TT;
        #pragma unroll
        for (int r = 0; r < RPGB; ++r) t0 = min(t0, lz[r] + 1);
        // t0 is group-uniform (same rows, same data, all 4 WGs).

        // ---- 128 packed weight regs: 4 cols x 2 gates x 16 h'-pairs ----
        const uint16_t* Wfr = (const uint16_t*)Wfc;
        const uint16_t* Wir = (const uint16_t*)Wic;
        uint32_t wf0[16], wf1[16], wf2[16], wf3[16];
        uint32_t wi0[16], wi1[16], wi2[16], wi3[16];
        #pragma unroll
        for (int p = 0; p < 16; ++p) {
            const int hp = chunk * 32 + 2 * p;
            const int b0 = hp * HD + h0 + cp, b1 = (hp + 1) * HD + h0 + cp;
            wf0[p] = (uint32_t)Wfr[b0]      | ((uint32_t)Wfr[b1]      << 16);
            wf1[p] = (uint32_t)Wfr[b0 + 32] | ((uint32_t)Wfr[b1 + 32] << 16);
            wf2[p] = (uint32_t)Wfr[b0 + 64] | ((uint32_t)Wfr[b1 + 64] << 16);
            wf3[p] = (uint32_t)Wfr[b0 + 96] | ((uint32_t)Wfr[b1 + 96] << 16);
            wi0[p] = (uint32_t)Wir[b0]      | ((uint32_t)Wir[b1]      << 16);
            wi1[p] = (uint32_t)Wir[b0 + 32] | ((uint32_t)Wir[b1 + 32] << 16);
            wi2[p] = (uint32_t)Wir[b0 + 64] | ((uint32_t)Wir[b1 + 64] << 16);
            wi3[p] = (uint32_t)Wir[b0 + 96] | ((uint32_t)Wir[b1 + 96] << 16);
        }
        #pragma unroll
        for (int p = 0; p < 16; ++p)
            asm volatile("" : "+v"(wf0[p]), "+v"(wf1[p]), "+v"(wf2[p]), "+v"(wf3[p]),
                              "+v"(wi0[p]), "+v"(wi1[p]), "+v"(wi2[p]), "+v"(wi3[p]));

        const bool isUpd = (tid < COLSB * RPGB);      // 256 update threads
        const int uc = tid & 127, ur = tid >> 7;      // (col, row)

        // ---- owner init: tag t0, value bf16(0) in buf[t0&1] ----
        // (init_k zeroed both buffers -> stale tags are 0; t0==0 matches the
        // memset pattern with value 0, which IS the correct initial state.)
        if (isUpd && t0 > 0) {
            uint32_t* b0 = (uint32_t*)((t0 & 1) ? C1 : C0);
            cstu(b0 + (r0 + ur) * HD + h0 + uc, (uint32_t)t0 & 0xFFFFu);
        }
        // no barrier: consumers spin on the tags themselves.

        float Creg = 0.0f;
        const int srow = tid >> 8;        // 0..1
        const int spr  = tid & 255;       // h'-pair index

        for (int t = t0; t < TT; ++t) {
            // re-pin weights every iteration (r7/r8/r10 lesson)
            #pragma unroll
            for (int p = 0; p < 16; ++p)
                asm volatile("" : "+v"(wf0[p]), "+v"(wf1[p]), "+v"(wf2[p]), "+v"(wf3[p]),
                                  "+v"(wi0[p]), "+v"(wi1[p]), "+v"(wi2[p]), "+v"(wi3[p]));

            const uint32_t* curT = (const uint32_t*)((t & 1) ? C1 : C0);
            uint32_t*       nxtT = (uint32_t*)((t & 1) ? C0 : C1);

            // ---- prefetch G gate operands (in flight during the spin) ----
            float gf = 0.f, gi = 0.f, sgc = 0.f;
            int cl = 1;
            if (isUpd) {
                cl = idx[ur * TT + t];
                const float* Gr = G + cl * 2048;
                gf  = Gr[h0 + uc];
                gi  = Gr[512 + h0 + uc];
                sgc = Gr[1536 + h0 + uc];
            }

            // ---- stage C(t): spin on tag==t, pack 2 bf16 -> 1 LDS word ----
            {
                const uint64_t* src = (const uint64_t*)(
                    curT + (r0 + srow) * HD + 2 * spr);
                const uint32_t exp = (uint32_t)t & 0xFFFFu;
                uint32_t w0, w1;
                for (;;) {
                    const uint64_t d = cldu8(src);
                    w0 = (uint32_t)d;
                    w1 = (uint32_t)(d >> 32);
                    if ((((w0 ^ exp) | (w1 ^ exp)) & 0xFFFFu) == 0u) break;
                }
                CbS[srow * CBW + spr] = (w0 >> 16) | (w1 & 0xFFFF0000u);
            }
            __syncthreads();

            // ---- 4-col packed dot over 32 h' (16 pairs), both rows ----
            float f0[RPGB], f1[RPGB], f2[RPGB], f3[RPGB];
            float i0[RPGB], i1[RPGB], i2[RPGB], i3[RPGB];
            #pragma unroll
            for (int r = 0; r < RPGB; ++r) {
                f0[r] = 0.f; f1[r] = 0.f; f2[r] = 0.f; f3[r] = 0.f;
                i0[r] = 0.f; i1[r] = 0.f; i2[r] = 0.f; i3[r] = 0.f;
            }
            {
                const int cb = chunk * 16;    // u32 word base of the chunk
                #pragma unroll
                for (int hh = 0; hh < 4; ++hh) {
                    #pragma unroll
                    for (int r = 0; r < RPGB; ++r) {
                        const uint4 cv = *reinterpret_cast<const uint4*>(
                            CbS + r * CBW + cb + 4 * hh);
                        const int p = 4 * hh;
                        DOT2(f0[r], wf0[p + 0], cv.x); DOT2(f0[r], wf0[p + 1], cv.y);
                        DOT2(f0[r], wf0[p + 2], cv.z); DOT2(f0[r], wf0[p + 3], cv.w);
                        DOT2(f1[r], wf1[p + 0], cv.x); DOT2(f1[r], wf1[p + 1], cv.y);
                        DOT2(f1[r], wf1[p + 2], cv.z); DOT2(f1[r], wf1[p + 3], cv.w);
                        DOT2(f2[r], wf2[p + 0], cv.x); DOT2(f2[r], wf2[p + 1], cv.y);
                        DOT2(f2[r], wf2[p + 2], cv.z); DOT2(f2[r], wf2[p + 3], cv.w);
                        DOT2(f3[r], wf3[p + 0], cv.x); DOT2(f3[r], wf3[p + 1], cv.y);
                        DOT2(f3[r], wf3[p + 2], cv.z); DOT2(f3[r], wf3[p + 3], cv.w);
                        DOT2(i0[r], wi0[p + 0], cv.x); DOT2(i0[r], wi0[p + 1], cv.y);
                        DOT2(i0[r], wi0[p + 2], cv.z); DOT2(i0[r], wi0[p + 3], cv.w);
                        DOT2(i1[r], wi1[p + 0], cv.x); DOT2(i1[r], wi1[p + 1], cv.y);
                        DOT2(i1[r], wi1[p + 2], cv.z); DOT2(i1[r], wi1[p + 3], cv.w);
                        DOT2(i2[r], wi2[p + 0], cv.x); DOT2(i2[r], wi2[p + 1], cv.y);
                        DOT2(i2[r], wi2[p + 2], cv.z); DOT2(i2[r], wi2[p + 3], cv.w);
                        DOT2(i3[r], wi3[p + 0], cv.x); DOT2(i3[r], wi3[p + 1], cv.y);
                        DOT2(i3[r], wi3[p + 2], cv.z); DOT2(i3[r], wi3[p + 3], cv.w);
                    }
                }
            }
            {
                float2* p0 = part2 + (chunk * 128 + cp)      * PSTB;
                float2* p1 = part2 + (chunk * 128 + cp + 32) * PSTB;
                float2* p2 = part2 + (chunk * 128 + cp + 64) * PSTB;
                float2* p3 = part2 + (chunk * 128 + cp + 96) * PSTB;
                #pragma unroll
                for (int r = 0; r < RPGB; ++r) {
                    p0[r] = make_float2(f0[r], i0[r]);
                    p1[r] = make_float2(f1[r], i1[r]);
                    p2[r] = make_float2(f2[r], i2[r]);
                    p3[r] = make_float2(f3[r], i3[r]);
                }
            }
            __syncthreads();
            // (stagers for t+1 may run ahead now; CbS rewrite is safe: it
            // requires observing tag t+1, which requires every local thread
            // to have passed this sync -> all dot reads of CbS are done.)

            // ---- update + tagged publish: thread < 256 owns (uc, ur) ----
            if (isUpd) {
                float df = 0.f, di = 0.f;
                #pragma unroll
                for (int ch = 0; ch < 16; ++ch) {
                    const float2 v = part2[(ch * 128 + uc) * PSTB + ur];
                    df += v.x;
                    di += v.y;
                }
                float Cn = sgc * sigf(gi + di) + Creg * sigf(gf + df);
                Cn = (cl > 0) ? Cn : 0.0f;
                Creg = Cn;
                const uint32_t vb = pkbf(Cn, Cn);     // low16 = bf16(Cn)
                cstu(nxtT + (r0 + ur) * HD + h0 + uc,
                     (vb << 16) | ((uint32_t)(t + 1) & 0xFFFFu));
            }
            // no barrier, no drain: consumers spin on the tag.
        }

        // ---- o-gate + h. C(T-1) is ALREADY in CbS (staged at the final
        // iteration; zeros if t0==TT). Unpack to f32 Cs, then r7 epilogue. --
        {
            const int rr = tid >> 8, wi = tid & 255;
            const uint32_t w = CbS[rr * CBW + wi];
            Cs[rr * CPAD + cpi(2 * wi)]     = __uint_as_float((w & 0xFFFFu) << 16);
            Cs[rr * CPAD + cpi(2 * wi + 1)] = __uint_as_float(w & 0xFFFF0000u);
            __syncthreads();

            // thread = (oc = tid&127 col, och = tid>>7: 4 chunks x 128 h')
            const int oc = tid & 127, och = tid >> 7;
            float ao0 = 0.f, ao1 = 0.f;
            #pragma unroll 4
            for (int k = 0; k < 128; ++k) {
                const int hp  = och * 128 + k;
                const int hpp = cpi(hp);
                const float wo = ldv<BF>(Woc, hp * HD + h0 + oc);
                ao0 += wo * Cs[0 * CPAD + hpp];
                ao1 += wo * Cs[1 * CPAD + hpp];
            }
            part2[(och * 128 + oc) * PSTB] = make_float2(ao0, ao1);
            __syncthreads();
            if (isUpd) {
                float s = 0.f;
                #pragma unroll
                for (int ch = 0; ch < 4; ++ch) {
                    const float2 v = part2[(ch * 128 + uc) * PSTB];
                    s += ur ? v.y : v.x;
                }
                const int cl2 = idx[ur * TT + TT - 1];
                const float o = sigf(G[cl2 * 2048 + 1024 + h0 + uc] + s);
                Hfb[(r0 + ur) * HD + h0 + uc] = tanhf(Creg) * o;
            }
        }
    } else {
        // ============ f32 path: r2-proven 8-WG clique (fallback) ==========
        const int grp   = blk >> 3;       // 0..31
        const int rank  = blk & 7;        // 0..7
        const int r0    = grp * RPGF;
        const int h0    = rank * COLSF;
        const int cp    = tid & 15;       // cols cp, +16, +32, +48
        const int chunk = tid >> 4;       // 0..31 (16 h' each)
        unsigned* bar = bars + grp * 32;

        idx[tid]        = x[r0 * TT + tid];
        idx[tid + 512]  = x[r0 * TT + tid + 512];
        idx[tid + 1024] = x[r0 * TT + tid + 1024];
        idx[tid + 1536] = x[r0 * TT + tid + 1536];
        if (tid < RPGF) lz[tid] = -1;
        __syncthreads();
        #pragma unroll
        for (int r = 0; r < RPGF; ++r)
            if (idx[r * TT + tid] == 0) atomicMax(&lz[r], tid);
        __syncthreads();
        int t0 = TT;
        #pragma unroll
        for (int r = 0; r < RPGF; ++r) t0 = min(t0, lz[r] + 1);

        float wf0[16], wf1[16], wf2[16], wf3[16];
        float wi0[16], wi1[16], wi2[16], wi3[16];
        #pragma unroll
        for (int k = 0; k < 16; ++k) {
            const int hp = chunk * 16 + k;
            wf0[k] = ldv<BF>(Wfc, hp * HD + h0 + cp);
            wf1[k] = ldv<BF>(Wfc, hp * HD + h0 + cp + 16);
            wf2[k] = ldv<BF>(Wfc, hp * HD + h0 + cp + 32);
            wf3[k] = ldv<BF>(Wfc, hp * HD + h0 + cp + 48);
            wi0[k] = ldv<BF>(Wic, hp * HD + h0 + cp);
            wi1[k] = ldv<BF>(Wic, hp * HD + h0 + cp + 16);
            wi2[k] = ldv<BF>(Wic, hp * HD + h0 + cp + 32);
            wi3[k] = ldv<BF>(Wic, hp * HD + h0 + cp + 48);
        }
        #pragma unroll
        for (int k = 0; k < 16; ++k)
            asm volatile("" : "+v"(wf0[k]), "+v"(wf1[k]), "+v"(wf2[k]), "+v"(wf3[k]),
                              "+v"(wi0[k]), "+v"(wi1[k]), "+v"(wi2[k]), "+v"(wi3[k]));

        const bool isUpd = (tid < COLSF * RPGF);
        const int uc = tid & 63, ur = tid >> 6;
        const int pe = cpi(tid);

        if (isUpd) {
            cst(&C0[(r0 + ur) * HD + h0 + uc], 0.0f);
            cst(&C1[(r0 + ur) * HD + h0 + uc], 0.0f);
        }
        gbarrier(bar, &bi, GWGF);

        float Creg = 0.0f;
        for (int t = t0; t < TT; ++t) {
            #pragma unroll
            for (int k = 0; k < 16; ++k)
                asm volatile("" : "+v"(wf0[k]), "+v"(wf1[k]), "+v"(wf2[k]), "+v"(wf3[k]),
                                  "+v"(wi0[k]), "+v"(wi1[k]), "+v"(wi2[k]), "+v"(wi3[k]));

            const float* cur = (t & 1) ? C1 : C0;
            float*       nxt = (t & 1) ? C0 : C1;

            float gf = 0.f, gi = 0.f, sgc = 0.f;
            int cl = 1;
            if (isUpd) {
                cl = idx[ur * TT + t];
                const float* Gr = G + cl * 2048;
                gf  = Gr[h0 + uc];
                gi  = Gr[512 + h0 + uc];
                sgc = Gr[1536 + h0 + uc];
            }

            {
                const float v0 = cld(cur + (r0 + 0) * HD + tid);
                const float v1 = cld(cur + (r0 + 1) * HD + tid);
                const float v2 = cld(cur + (r0 + 2) * HD + tid);
                const float v3 = cld(cur + (r0 + 3) * HD + tid);
                Cs[0 * CPAD + pe] = v0;
                Cs[1 * CPAD + pe] = v1;
                Cs[2 * CPAD + pe] = v2;
                Cs[3 * CPAD + pe] = v3;
            }
            __syncthreads();

            float f0[RPGF], f1[RPGF], f2[RPGF], f3[RPGF];
            float i0[RPGF], i1[RPGF], i2[RPGF], i3[RPGF];
            #pragma unroll
            for (int r = 0; r < RPGF; ++r) {
                f0[r] = 0.f; f1[r] = 0.f; f2[r] = 0.f; f3[r] = 0.f;
                i0[r] = 0.f; i1[r] = 0.f; i2[r] = 0.f; i3[r] = 0.f;
            }
            {
                const int cb = chunk * 5;
                #pragma unroll
                for (int j = 0; j < 4; ++j) {
                    #pragma unroll
                    for (int r = 0; r < RPGF; ++r) {
                        const float4 cv = reinterpret_cast<const float4*>(
                            Cs + r * CPAD)[cb + j];
                        f0[r] += wf0[4*j]*cv.x + wf0[4*j+1]*cv.y + wf0[4*j+2]*cv.z + wf0[4*j+3]*cv.w;
                        f1[r] += wf1[4*j]*cv.x + wf1[4*j+1]*cv.y + wf1[4*j+2]*cv.z + wf1[4*j+3]*cv.w;
                        f2[r] += wf2[4*j]*cv.x + wf2[4*j+1]*cv.y + wf2[4*j+2]*cv.z + wf2[4*j+3]*cv.w;
                        f3[r] += wf3[4*j]*cv.x + wf3[4*j+1]*cv.y + wf3[4*j+2]*cv.z + wf3[4*j+3]*cv.w;
                        i0[r] += wi0[4*j]*cv.x + wi0[4*j+1]*cv.y + wi0[4*j+2]*cv.z + wi0[4*j+3]*cv.w;
                        i1[r] += wi1[4*j]*cv.x + wi1[4*j+1]*cv.y + wi1[4*j+2]*cv.z + wi1[4*j+3]*cv.w;
                        i2[r] += wi2[4*j]*cv.x + wi2[4*j+1]*cv.y + wi2[4*j+2]*cv.z + wi2[4*j+3]*cv.w;
                        i3[r] += wi3[4*j]*cv.x + wi3[4*j+1]*cv.y + wi3[4*j+2]*cv.z + wi3[4*j+3]*cv.w;
                    }
                }
            }
            {
                float2* p0 = part2 + (chunk * 64 + cp)      * PSTF;
                float2* p1 = part2 + (chunk * 64 + cp + 16) * PSTF;
                float2* p2 = part2 + (chunk * 64 + cp + 32) * PSTF;
                float2* p3 = part2 + (chunk * 64 + cp + 48) * PSTF;
                #pragma unroll
                for (int r = 0; r < RPGF; ++r) {
                    p0[r] = make_float2(f0[r], i0[r]);
                    p1[r] = make_float2(f1[r], i1[r]);
                    p2[r] = make_float2(f2[r], i2[r]);
                    p3[r] = make_float2(f3[r], i3[r]);
                }
            }
            __syncthreads();

            if (isUpd) {
                float df = 0.f, di = 0.f;
                #pragma unroll
                for (int ch = 0; ch < 32; ++ch) {
                    const float2 v = part2[(ch * 64 + uc) * PSTF + ur];
                    df += v.x;
                    di += v.y;
                }
                float Cn = sgc * sigf(gi + di) + Creg * sigf(gf + df);
                Cn = (cl > 0) ? Cn : 0.0f;
                Creg = Cn;
                cst(&nxt[(r0 + ur) * HD + h0 + uc], Cn);
            }
            gbarrier(bar, &bi, GWGF);
        }

        // ---- o-gate + h (r2 epilogue) ----
        {
            const float v0 = cld(C1 + (r0 + 0) * HD + tid);
            const float v1 = cld(C1 + (r0 + 1) * HD + tid);
            const float v2 = cld(C1 + (r0 + 2) * HD + tid);
            const float v3 = cld(C1 + (r0 + 3) * HD + tid);
            Cs[0 * CPAD + pe] = v0;
            Cs[1 * CPAD + pe] = v1;
            Cs[2 * CPAD + pe] = v2;
            Cs[3 * CPAD + pe] = v3;
            __syncthreads();

            const int oc = tid & 63, och = tid >> 6;
            float ao[RPGF];
            #pragma unroll
            for (int r = 0; r < RPGF; ++r) ao[r] = 0.0f;
            #pragma unroll 4
            for (int k = 0; k < 64; ++k) {
                const int hp = och * 64 + k;
                const int hpp = cpi(hp);
                const float wo = ldv<BF>(Woc, hp * HD + h0 + oc);
                #pragma unroll
                for (int r = 0; r < RPGF; ++r)
                    ao[r] += wo * Cs[r * CPAD + hpp];
            }
            {
                float2* pp = part2 + (och * 64 + oc) * PSTF;
                #pragma unroll
                for (int r2 = 0; r2 < RPGF / 2; ++r2)
                    pp[r2] = make_float2(ao[2 * r2], ao[2 * r2 + 1]);
            }
            __syncthreads();
            if (isUpd) {
                float s = 0.f;
                #pragma unroll
                for (int ch = 0; ch < 8; ++ch) {
                    const float2 v = part2[(ch * 64 + uc) * PSTF + (ur >> 1)];
                    s += (ur & 1) ? v.y : v.x;
                }
                const int cl2 = idx[ur * TT + TT - 1];
                const float o = sigf(G[cl2 * 2048 + 1024 + h0 + uc] + s);
                Hfb[(r0 + ur) * HD + h0 + uc] = tanhf(Creg) * o;
            }
        }
    }
}

// ---------------------------------------------------------------------------
// Projection + log_softmax, one WG per batch row.
// ---------------------------------------------------------------------------
template <bool BF>
__global__ __launch_bounds__(128) void proj(
    const int* __restrict__ flag, const float* __restrict__ Hfb,
    const void* __restrict__ Wph, const void* __restrict__ bp,
    void* __restrict__ out)
{
    if (*flag != (BF ? 1 : 0)) return;
    __shared__ __align__(16) float hv[HD];
    __shared__ float p_s[NCLS];
    __shared__ float lse_s;
    const int b   = blockIdx.x;
    const int tid = threadIdx.x;

    reinterpret_cast<float4*>(hv)[tid] =
        reinterpret_cast<const float4*>(Hfb + b * HD)[tid];
    __syncthreads();

    if (tid < NCLS) {
        float p = ldv<BF>(bp, tid);
        for (int h = 0; h < HD; ++h)
            p += hv[h] * ldv<BF>(Wph, h * NCLS + tid);
        p_s[tid] = p;
    }
    __syncthreads();
    if (tid == 0) {
        float m = -1e30f;
        for (int n = 0; n < NCLS; ++n) m = fmaxf(m, p_s[n]);
        float sum = 0.0f;
        for (int n = 0; n < NCLS; ++n) sum += expf(p_s[n] - m);
        lse_s = m + logf(sum);
    }
    __syncthreads();
    if (tid < NCLS) {
        const float v = p_s[tid] - lse_s;
        if constexpr (BF) ((bf16*)out)[b * NCLS + tid] = __float2bfloat16(v);
        else              ((float*)out)[b * NCLS + tid] = v;
    }
}

// ---------------------------------------------------------------------------
extern "C" void kernel_launch(void* const* d_in, const int* in_sizes, int n_in,
                              void* d_out, int out_size, void* d_ws, size_t ws_size,
                              hipStream_t stream) {
    const int*  x   = (const int*)d_in[0];
    const void* emb = d_in[1];
    const void* Wfx = d_in[2];
    const void* Wfc = d_in[3];
    const void* bfv = d_in[4];
    const void* Wix = d_in[5];
    const void* Wic = d_in[6];
    const void* biv = d_in[7];
    const void* Wox = d_in[8];
    const void* Woc = d_in[9];
    const void* bov = d_in[10];
    const void* Wcx = d_in[11];
    const void* bcv = d_in[12];
    const void* Wph = d_in[13];
    const void* bp  = d_in[14];

    int*      flag = (int*)((char*)d_ws + WS_FLAG);
    unsigned* bars = (unsigned*)((char*)d_ws + WS_BAR);
    float*    G    = (float*)((char*)d_ws + WS_G);
    float*    C0   = (float*)((char*)d_ws + WS_C0);
    float*    C1   = (float*)((char*)d_ws + WS_C1);
    float*    Hfb  = (float*)((char*)d_ws + WS_HFB);

    init_k<<<8, 1024, 0, stream>>>((const uint32_t*)emb, flag, bars,
                                   (uint32_t*)C0, (uint32_t*)C1);

    build_G<false><<<dim3(NEMB, 8), 256, 0, stream>>>(flag, emb, Wfx, Wix, Wox, Wcx,
                                                      bfv, biv, bov, bcv, G);
    build_G<true ><<<dim3(NEMB, 8), 256, 0, stream>>>(flag, emb, Wfx, Wix, Wox, Wcx,
                                                      bfv, biv, bov, bcv, G);

    {
        // 256 blocks either way: bf16 path reads blk as 64x4, f32 as 32x8.
        void* args[] = {(void*)&flag, (void*)&x, (void*)&G,
                        (void*)&Wfc, (void*)&Wic, (void*)&Woc,
                        (void*)&C0, (void*)&C1, (void*)&Hfb, (void*)&bars};
        hipLaunchCooperativeKernel((const void*)recur_bs<false>, dim3(256), dim3(THR),
                                   args, 0, stream);
        hipLaunchCooperativeKernel((const void*)recur_bs<true>, dim3(256), dim3(THR),
                                   args, 0, stream);
    }

    proj<false><<<BB, 128, 0, stream>>>(flag, Hfb, Wph, bp, d_out);
    proj<true ><<<BB, 128, 0, stream>>>(flag, Hfb, Wph, bp, d_out);
}